// Round 1
// baseline (825.761 us; speedup 1.0000x reference)
//
#include <hip/hip_runtime.h>

// ---------------- CSR construction ----------------

__global__ void zero_i32(int* __restrict__ p, int n) {
    int i = blockIdx.x * blockDim.x + threadIdx.x;
    if (i < n) p[i] = 0;
}

__global__ void hist_kernel(const int* __restrict__ dst, int* __restrict__ counts, int E) {
    int i = blockIdx.x * blockDim.x + threadIdx.x;
    if (i < E) atomicAdd(&counts[dst[i]], 1);
}

// single-workgroup chunked Hillis-Steele exclusive scan
__global__ void scan_kernel(const int* __restrict__ counts, int* __restrict__ rowptr, int n) {
    __shared__ int sdata[1024];
    __shared__ int carry_s;
    if (threadIdx.x == 0) carry_s = 0;
    __syncthreads();
    for (int base = 0; base < n; base += 1024) {
        int i = base + threadIdx.x;
        int v = (i < n) ? counts[i] : 0;
        sdata[threadIdx.x] = v;
        __syncthreads();
        for (int off = 1; off < 1024; off <<= 1) {
            int t = (threadIdx.x >= off) ? sdata[threadIdx.x - off] : 0;
            __syncthreads();
            sdata[threadIdx.x] += t;
            __syncthreads();
        }
        int incl = sdata[threadIdx.x];
        if (i < n) rowptr[i] = carry_s + incl - v;   // exclusive
        __syncthreads();
        if (threadIdx.x == 0) carry_s += sdata[1023];
        __syncthreads();
    }
    if (threadIdx.x == 0) rowptr[n] = carry_s;
}

__global__ void scatter_kernel(const int* __restrict__ dst, const int* __restrict__ rowptr,
                               int* __restrict__ cursor, int* __restrict__ eidx, int E) {
    int i = blockIdx.x * blockDim.x + threadIdx.x;
    if (i < E) {
        int d = dst[i];
        int p = rowptr[d] + atomicAdd(&cursor[d], 1);
        eidx[p] = i;
    }
}

// ---------------- fused GEMM + el/er projection ----------------
// feat[n][j] = sum_k A'[n][k] * W[k][j],  A' = RELU_IN ? relu(A + bin) : A
// el[n][h] = sum_d feat[n][h][d] * al[h][d]   (same for er)
template <int FIN, int FOUT, int D, bool RELU_IN>
__global__ void gemm_att(const float* __restrict__ A, const float* __restrict__ bin,
                         const float* __restrict__ W, const float* __restrict__ al,
                         const float* __restrict__ ar, float* __restrict__ feat,
                         float* __restrict__ el, float* __restrict__ er, int N) {
    constexpr int R = 16;
    constexpr int H = FOUT / D;
    __shared__ float As[R][FIN];
    const int j = threadIdx.x;           // blockDim.x == FOUT
    const int h = j / D;
    const float alv = al[j];
    const float arv = ar[j];
    const int row0 = blockIdx.x * R;

    for (int idx = threadIdx.x; idx < R * FIN; idx += blockDim.x) {
        int r = idx / FIN, k = idx % FIN;
        int rr = row0 + r;
        float v = 0.f;
        if (rr < N) {
            v = A[(size_t)rr * FIN + k];
            if constexpr (RELU_IN) {
                v += bin[k];
                v = v > 0.f ? v : 0.f;
            }
        }
        As[r][k] = v;
    }
    __syncthreads();

    float acc[R];
#pragma unroll
    for (int r = 0; r < R; r++) acc[r] = 0.f;
    for (int k = 0; k < FIN; k++) {
        float w = W[(size_t)k * FOUT + j];
#pragma unroll
        for (int r = 0; r < R; r++) acc[r] += As[r][k] * w;
    }

#pragma unroll
    for (int r = 0; r < R; r++) {
        int rr = row0 + r;
        if (rr >= N) break;            // uniform across the wave (same r, row0)
        float v = acc[r];
        feat[(size_t)rr * FOUT + j] = v;
        float vl = v * alv, vr = v * arv;
#pragma unroll
        for (int off = D / 2; off >= 1; off >>= 1) {
            vl += __shfl_xor(vl, off);
            vr += __shfl_xor(vr, off);
        }
        if ((j % D) == 0) {
            el[(size_t)rr * H + h] = vl;
            er[(size_t)rr * H + h] = vr;
        }
    }
}

// ---------------- per-dst-node edge softmax + aggregation ----------------
template <int H, int D>
__global__ void agg_kernel(const float* __restrict__ feat, const float* __restrict__ el,
                           const float* __restrict__ er, const int* __restrict__ rowptr,
                           const int* __restrict__ eidx, const int* __restrict__ src,
                           float* __restrict__ out, int N) {
    constexpr int HD = H * D;
    const int tid = threadIdx.x;        // blockDim.x == HD
    const int h = tid / D;
    for (int node = blockIdx.x; node < N; node += gridDim.x) {
        int beg = rowptr[node], end = rowptr[node + 1];
        float erv = er[(size_t)node * H + h];
        // pass 1: online max + sum of exp
        float m = -3.4e38f, s = 0.f;
        for (int i = beg; i < end; i++) {
            int u = src[eidx[i]];
            float x = el[(size_t)u * H + h] + erv;
            x = x > 0.f ? x : 0.2f * x;
            if (x > m) {
                s = s * __expf(m - x) + 1.f;
                m = x;
            } else {
                s += __expf(x - m);
            }
        }
        float inv = (s > 0.f) ? 1.f / s : 0.f;
        // pass 2: weighted gather
        float acc = 0.f;
        for (int i = beg; i < end; i++) {
            int u = src[eidx[i]];
            float x = el[(size_t)u * H + h] + erv;
            x = x > 0.f ? x : 0.2f * x;
            float a = __expf(x - m) * inv;
            acc += a * feat[(size_t)u * HD + tid];
        }
        out[(size_t)node * HD + tid] = acc;
    }
}

// ---------------- batched-graph mean readout ----------------

__device__ __forceinline__ int lower_bound_i(const int* __restrict__ a, int n, int key) {
    int lo = 0, hi = n;
    while (lo < hi) {
        int mid = (lo + hi) >> 1;
        if (a[mid] < key) lo = mid + 1; else hi = mid;
    }
    return lo;
}

__global__ void readout_partial(const float* __restrict__ agg, const int* __restrict__ gid,
                                float* __restrict__ part, int N, int C, int SL) {
    int g = blockIdx.x / SL, slice = blockIdx.x % SL;
    int c = threadIdx.x;                 // blockDim.x == C
    int start = lower_bound_i(gid, N, g);
    int end = lower_bound_i(gid, N, g + 1);
    float sum = 0.f;
    for (int n = start + slice; n < end; n += SL) sum += agg[(size_t)n * C + c];
    part[((size_t)g * SL + slice) * C + c] = sum;
}

__global__ void readout_final(const float* __restrict__ part, const float* __restrict__ b3,
                              const int* __restrict__ gid, float* __restrict__ out,
                              int N, int C, int SL) {
    int g = blockIdx.x, c = threadIdx.x;
    int start = lower_bound_i(gid, N, g);
    int end = lower_bound_i(gid, N, g + 1);
    int cnt = end - start;
    float s = 0.f;
    for (int k = 0; k < SL; k++) s += part[((size_t)g * SL + k) * C + c];
    out[(size_t)g * C + c] = (cnt > 0) ? s / (float)cnt + b3[c] : 0.f;
}

// ---------------- launch ----------------

extern "C" void kernel_launch(void* const* d_in, const int* in_sizes, int n_in,
                              void* d_out, int out_size, void* d_ws, size_t ws_size,
                              hipStream_t stream) {
    const float* feat0 = (const float*)d_in[0];
    const int* src = (const int*)d_in[1];
    const int* dst = (const int*)d_in[2];
    const int* gid = (const int*)d_in[3];
    const float* W1 = (const float*)d_in[4];
    const float* al1 = (const float*)d_in[5];
    const float* ar1 = (const float*)d_in[6];
    const float* b1 = (const float*)d_in[7];
    const float* W2 = (const float*)d_in[8];
    const float* al2 = (const float*)d_in[9];
    const float* ar2 = (const float*)d_in[10];
    const float* b2 = (const float*)d_in[11];
    const float* W3 = (const float*)d_in[12];
    const float* al3 = (const float*)d_in[13];
    const float* ar3 = (const float*)d_in[14];
    const float* b3 = (const float*)d_in[15];

    const int N = in_sizes[0] / 6;       // 30000
    const int E = in_sizes[1];           // 480000
    const int G = 64;
    const int SL = 8;
    float* out = (float*)d_out;

    char* wsp = (char*)d_ws;
    auto alloc = [&](size_t bytes) -> char* {
        char* p = wsp;
        wsp += (bytes + 255) & ~(size_t)255;
        return p;
    };
    int* counts  = (int*)alloc((size_t)N * 4);
    int* rowptr  = (int*)alloc((size_t)(N + 1) * 4);
    int* cursor  = (int*)alloc((size_t)N * 4);
    int* eidx    = (int*)alloc((size_t)E * 4);
    float* el    = (float*)alloc((size_t)N * 4 * 4);
    float* er    = (float*)alloc((size_t)N * 4 * 4);
    float* featA = (float*)alloc((size_t)N * 256 * 4);
    float* aggB  = (float*)alloc((size_t)N * 256 * 4);
    float* part  = (float*)alloc((size_t)G * SL * 256 * 4);

    // CSR build
    zero_i32<<<dim3((N + 255) / 256), dim3(256), 0, stream>>>(counts, N);
    zero_i32<<<dim3((N + 255) / 256), dim3(256), 0, stream>>>(cursor, N);
    hist_kernel<<<dim3((E + 255) / 256), dim3(256), 0, stream>>>(dst, counts, E);
    scan_kernel<<<dim3(1), dim3(1024), 0, stream>>>(counts, rowptr, N);
    scatter_kernel<<<dim3((E + 255) / 256), dim3(256), 0, stream>>>(dst, rowptr, cursor, eidx, E);

    const int gemmGrid = (N + 15) / 16;

    // layer 1
    gemm_att<6, 128, 32, false><<<dim3(gemmGrid), dim3(128), 0, stream>>>(
        feat0, nullptr, W1, al1, ar1, featA, el, er, N);
    agg_kernel<4, 32><<<dim3(8192), dim3(128), 0, stream>>>(
        featA, el, er, rowptr, eidx, src, aggB, N);

    // layer 2 (relu(prev + b1) fused into A load)
    gemm_att<128, 128, 32, true><<<dim3(gemmGrid), dim3(128), 0, stream>>>(
        aggB, b1, W2, al2, ar2, featA, el, er, N);
    agg_kernel<4, 32><<<dim3(8192), dim3(128), 0, stream>>>(
        featA, el, er, rowptr, eidx, src, aggB, N);

    // layer 3
    gemm_att<128, 256, 64, true><<<dim3(gemmGrid), dim3(256), 0, stream>>>(
        aggB, b2, W3, al3, ar3, featA, el, er, N);
    agg_kernel<4, 64><<<dim3(8192), dim3(256), 0, stream>>>(
        featA, el, er, rowptr, eidx, src, aggB, N);

    // readout: mean over nodes per graph, + b3
    readout_partial<<<dim3(G * SL), dim3(256), 0, stream>>>(aggB, gid, part, N, 256, SL);
    readout_final<<<dim3(G), dim3(256), 0, stream>>>(part, b3, gid, out, N, 256, SL);
}

// Round 2
// 426.314 us; speedup vs baseline: 1.9370x; 1.9370x over previous
//
#include <hip/hip_runtime.h>

// ---------------- CSR construction ----------------

__global__ void zero_i32(int* __restrict__ p, int n) {
    int i = blockIdx.x * blockDim.x + threadIdx.x;
    if (i < n) p[i] = 0;
}

__global__ void hist_kernel(const int* __restrict__ dst, int* __restrict__ counts, int E) {
    int i = blockIdx.x * blockDim.x + threadIdx.x;
    if (i < E) atomicAdd(&counts[dst[i]], 1);
}

// single-workgroup chunked Hillis-Steele exclusive scan
__global__ void scan_kernel(const int* __restrict__ counts, int* __restrict__ rowptr, int n) {
    __shared__ int sdata[1024];
    __shared__ int carry_s;
    if (threadIdx.x == 0) carry_s = 0;
    __syncthreads();
    for (int base = 0; base < n; base += 1024) {
        int i = base + threadIdx.x;
        int v = (i < n) ? counts[i] : 0;
        sdata[threadIdx.x] = v;
        __syncthreads();
        for (int off = 1; off < 1024; off <<= 1) {
            int t = (threadIdx.x >= off) ? sdata[threadIdx.x - off] : 0;
            __syncthreads();
            sdata[threadIdx.x] += t;
            __syncthreads();
        }
        int incl = sdata[threadIdx.x];
        if (i < n) rowptr[i] = carry_s + incl - v;   // exclusive
        __syncthreads();
        if (threadIdx.x == 0) carry_s += sdata[1023];
        __syncthreads();
    }
    if (threadIdx.x == 0) rowptr[n] = carry_s;
}

// scatter edges into dst-sorted order; store src/dst per sorted slot directly
__global__ void scatter_kernel(const int* __restrict__ src, const int* __restrict__ dst,
                               const int* __restrict__ rowptr, int* __restrict__ cursor,
                               int* __restrict__ srcs, int* __restrict__ dsts, int E) {
    int i = blockIdx.x * blockDim.x + threadIdx.x;
    if (i < E) {
        int d = dst[i];
        int p = rowptr[d] + atomicAdd(&cursor[d], 1);
        srcs[p] = src[i];
        dsts[p] = d;
    }
}

// ---------------- fused GEMM + el/er projection ----------------
// feat[n][j] = sum_k A'[n][k] * W[k][j],  A' = RELU_IN ? relu(A + bin) : A
// el[n][h] = sum_d feat[n][h][d] * al[h][d]   (same for er)
template <int FIN, int FOUT, int D, bool RELU_IN>
__global__ void gemm_att(const float* __restrict__ A, const float* __restrict__ bin,
                         const float* __restrict__ W, const float* __restrict__ al,
                         const float* __restrict__ ar, float* __restrict__ feat,
                         float* __restrict__ el, float* __restrict__ er, int N) {
    constexpr int R = 16;
    constexpr int H = FOUT / D;
    __shared__ float As[R][FIN];
    const int j = threadIdx.x;           // blockDim.x == FOUT
    const int h = j / D;
    const float alv = al[j];
    const float arv = ar[j];
    const int row0 = blockIdx.x * R;

    for (int idx = threadIdx.x; idx < R * FIN; idx += blockDim.x) {
        int r = idx / FIN, k = idx % FIN;
        int rr = row0 + r;
        float v = 0.f;
        if (rr < N) {
            v = A[(size_t)rr * FIN + k];
            if constexpr (RELU_IN) {
                v += bin[k];
                v = v > 0.f ? v : 0.f;
            }
        }
        As[r][k] = v;
    }
    __syncthreads();

    float acc[R];
#pragma unroll
    for (int r = 0; r < R; r++) acc[r] = 0.f;
    for (int k = 0; k < FIN; k++) {
        float w = W[(size_t)k * FOUT + j];
#pragma unroll
        for (int r = 0; r < R; r++) acc[r] += As[r][k] * w;
    }

#pragma unroll
    for (int r = 0; r < R; r++) {
        int rr = row0 + r;
        if (rr >= N) break;            // uniform across the wave (same r, row0)
        float v = acc[r];
        feat[(size_t)rr * FOUT + j] = v;
        float vl = v * alv, vr = v * arv;
#pragma unroll
        for (int off = D / 2; off >= 1; off >>= 1) {
            vl += __shfl_xor(vl, off);
            vr += __shfl_xor(vr, off);
        }
        if ((j % D) == 0) {
            el[(size_t)rr * H + h] = vl;
            er[(size_t)rr * H + h] = vr;
        }
    }
}

// ---------------- edge-parallel attention logits ----------------
// xbuf[i][h] = leaky_relu(el[srcs[i]][h] + er[dsts[i]][h]),  H == 4 (float4)
__global__ void edge_x_kernel(const int* __restrict__ srcs, const int* __restrict__ dsts,
                              const float4* __restrict__ el, const float4* __restrict__ er,
                              float4* __restrict__ xbuf, int E) {
    int i = blockIdx.x * blockDim.x + threadIdx.x;
    if (i >= E) return;
    int u = srcs[i], d = dsts[i];
    float4 l = el[u], r = er[d];
    float4 x;
    x.x = l.x + r.x; x.x = x.x > 0.f ? x.x : 0.2f * x.x;
    x.y = l.y + r.y; x.y = x.y > 0.f ? x.y : 0.2f * x.y;
    x.z = l.z + r.z; x.z = x.z > 0.f ? x.z : 0.2f * x.z;
    x.w = l.w + r.w; x.w = x.w > 0.f ? x.w : 0.2f * x.w;
    xbuf[i] = x;
}

// ---------------- per-dst-node edge softmax + aggregation ----------------
// one block per node; phase 1 parallel over edges within each head's D lanes,
// phase 2 unrolled x4 for memory-level parallelism on the feat gathers
template <int H, int D>
__global__ void agg_kernel(const float* __restrict__ feat, const float* __restrict__ xbuf,
                           const int* __restrict__ srcs, const int* __restrict__ rowptr,
                           float* __restrict__ out, int N) {
    constexpr int HD = H * D;
    const int tid = threadIdx.x;        // blockDim.x == HD
    const int h = tid / D;
    const int d = tid % D;
    const int node = blockIdx.x;
    if (node >= N) return;
    const int beg = rowptr[node], end = rowptr[node + 1];

    // phase 1: edge-parallel online softmax stats (per head)
    float m = -3.4e38f, s = 0.f;
    for (int i = beg + d; i < end; i += D) {
        float x = xbuf[(size_t)i * H + h];
        float mn = fmaxf(m, x);
        s = s * __expf(m - mn) + __expf(x - mn);
        m = mn;
    }
#pragma unroll
    for (int off = D / 2; off >= 1; off >>= 1) {
        float m2 = __shfl_xor(m, off);
        float s2 = __shfl_xor(s, off);
        float mn = fmaxf(m, m2);
        s = s * __expf(m - mn) + s2 * __expf(m2 - mn);
        m = mn;
    }
    const float inv = (s > 0.f) ? 1.f / s : 0.f;

    // phase 2: weighted gather, 4 independent accumulators for MLP
    float a0 = 0.f, a1 = 0.f, a2 = 0.f, a3 = 0.f;
    int i = beg;
    for (; i + 4 <= end; i += 4) {
        int u0 = srcs[i], u1 = srcs[i + 1], u2 = srcs[i + 2], u3 = srcs[i + 3];
        float x0 = xbuf[(size_t)i * H + h];
        float x1 = xbuf[(size_t)(i + 1) * H + h];
        float x2 = xbuf[(size_t)(i + 2) * H + h];
        float x3 = xbuf[(size_t)(i + 3) * H + h];
        float f0 = feat[(size_t)u0 * HD + tid];
        float f1 = feat[(size_t)u1 * HD + tid];
        float f2 = feat[(size_t)u2 * HD + tid];
        float f3 = feat[(size_t)u3 * HD + tid];
        a0 += __expf(x0 - m) * f0;
        a1 += __expf(x1 - m) * f1;
        a2 += __expf(x2 - m) * f2;
        a3 += __expf(x3 - m) * f3;
    }
    for (; i < end; i++) {
        int u = srcs[i];
        float x = xbuf[(size_t)i * H + h];
        a0 += __expf(x - m) * feat[(size_t)u * HD + tid];
    }
    out[(size_t)node * HD + tid] = ((a0 + a1) + (a2 + a3)) * inv;
}

// ---------------- batched-graph mean readout ----------------

__device__ __forceinline__ int lower_bound_i(const int* __restrict__ a, int n, int key) {
    int lo = 0, hi = n;
    while (lo < hi) {
        int mid = (lo + hi) >> 1;
        if (a[mid] < key) lo = mid + 1; else hi = mid;
    }
    return lo;
}

__global__ void readout_partial(const float* __restrict__ agg, const int* __restrict__ gid,
                                float* __restrict__ part, int N, int C, int SL) {
    int g = blockIdx.x / SL, slice = blockIdx.x % SL;
    int c = threadIdx.x;                 // blockDim.x == C
    int start = lower_bound_i(gid, N, g);
    int end = lower_bound_i(gid, N, g + 1);
    float sum = 0.f;
    for (int n = start + slice; n < end; n += SL) sum += agg[(size_t)n * C + c];
    part[((size_t)g * SL + slice) * C + c] = sum;
}

__global__ void readout_final(const float* __restrict__ part, const float* __restrict__ b3,
                              const int* __restrict__ gid, float* __restrict__ out,
                              int N, int C, int SL) {
    int g = blockIdx.x, c = threadIdx.x;
    int start = lower_bound_i(gid, N, g);
    int end = lower_bound_i(gid, N, g + 1);
    int cnt = end - start;
    float s = 0.f;
    for (int k = 0; k < SL; k++) s += part[((size_t)g * SL + k) * C + c];
    out[(size_t)g * C + c] = (cnt > 0) ? s / (float)cnt + b3[c] : 0.f;
}

// ---------------- launch ----------------

extern "C" void kernel_launch(void* const* d_in, const int* in_sizes, int n_in,
                              void* d_out, int out_size, void* d_ws, size_t ws_size,
                              hipStream_t stream) {
    const float* feat0 = (const float*)d_in[0];
    const int* src = (const int*)d_in[1];
    const int* dst = (const int*)d_in[2];
    const int* gid = (const int*)d_in[3];
    const float* W1 = (const float*)d_in[4];
    const float* al1 = (const float*)d_in[5];
    const float* ar1 = (const float*)d_in[6];
    const float* b1 = (const float*)d_in[7];
    const float* W2 = (const float*)d_in[8];
    const float* al2 = (const float*)d_in[9];
    const float* ar2 = (const float*)d_in[10];
    const float* b2 = (const float*)d_in[11];
    const float* W3 = (const float*)d_in[12];
    const float* al3 = (const float*)d_in[13];
    const float* ar3 = (const float*)d_in[14];
    const float* b3 = (const float*)d_in[15];

    const int N = in_sizes[0] / 6;       // 30000
    const int E = in_sizes[1];           // 480000
    const int G = 64;
    const int SL = 8;
    float* out = (float*)d_out;

    char* wsp = (char*)d_ws;
    auto alloc = [&](size_t bytes) -> char* {
        char* p = wsp;
        wsp += (bytes + 255) & ~(size_t)255;
        return p;
    };
    int* counts  = (int*)alloc((size_t)N * 4);
    int* rowptr  = (int*)alloc((size_t)(N + 1) * 4);
    int* cursor  = (int*)alloc((size_t)N * 4);
    int* srcs    = (int*)alloc((size_t)E * 4);
    int* dsts    = (int*)alloc((size_t)E * 4);
    float* xbuf  = (float*)alloc((size_t)E * 4 * 4);
    float* el    = (float*)alloc((size_t)N * 4 * 4);
    float* er    = (float*)alloc((size_t)N * 4 * 4);
    float* featA = (float*)alloc((size_t)N * 256 * 4);
    float* aggB  = (float*)alloc((size_t)N * 256 * 4);
    float* part  = (float*)alloc((size_t)G * SL * 256 * 4);

    // CSR build (dst-sorted edge list with materialized src/dst per slot)
    zero_i32<<<dim3((N + 255) / 256), dim3(256), 0, stream>>>(counts, N);
    zero_i32<<<dim3((N + 255) / 256), dim3(256), 0, stream>>>(cursor, N);
    hist_kernel<<<dim3((E + 255) / 256), dim3(256), 0, stream>>>(dst, counts, E);
    scan_kernel<<<dim3(1), dim3(1024), 0, stream>>>(counts, rowptr, N);
    scatter_kernel<<<dim3((E + 255) / 256), dim3(256), 0, stream>>>(
        src, dst, rowptr, cursor, srcs, dsts, E);

    const int gemmGrid = (N + 15) / 16;
    const int edgeGrid = (E + 255) / 256;

    // layer 1
    gemm_att<6, 128, 32, false><<<dim3(gemmGrid), dim3(128), 0, stream>>>(
        feat0, nullptr, W1, al1, ar1, featA, el, er, N);
    edge_x_kernel<<<dim3(edgeGrid), dim3(256), 0, stream>>>(
        srcs, dsts, (const float4*)el, (const float4*)er, (float4*)xbuf, E);
    agg_kernel<4, 32><<<dim3(N), dim3(128), 0, stream>>>(
        featA, xbuf, srcs, rowptr, aggB, N);

    // layer 2 (relu(prev + b1) fused into A load)
    gemm_att<128, 128, 32, true><<<dim3(gemmGrid), dim3(128), 0, stream>>>(
        aggB, b1, W2, al2, ar2, featA, el, er, N);
    edge_x_kernel<<<dim3(edgeGrid), dim3(256), 0, stream>>>(
        srcs, dsts, (const float4*)el, (const float4*)er, (float4*)xbuf, E);
    agg_kernel<4, 32><<<dim3(N), dim3(128), 0, stream>>>(
        featA, xbuf, srcs, rowptr, aggB, N);

    // layer 3
    gemm_att<128, 256, 64, true><<<dim3(gemmGrid), dim3(256), 0, stream>>>(
        aggB, b2, W3, al3, ar3, featA, el, er, N);
    edge_x_kernel<<<dim3(edgeGrid), dim3(256), 0, stream>>>(
        srcs, dsts, (const float4*)el, (const float4*)er, (float4*)xbuf, E);
    agg_kernel<4, 64><<<dim3(N), dim3(256), 0, stream>>>(
        featA, xbuf, srcs, rowptr, aggB, N);

    // readout: mean over nodes per graph, + b3
    readout_partial<<<dim3(G * SL), dim3(256), 0, stream>>>(aggB, gid, part, N, 256, SL);
    readout_final<<<dim3(G), dim3(256), 0, stream>>>(part, b3, gid, out, N, 256, SL);
}

// Round 3
// 386.926 us; speedup vs baseline: 2.1342x; 1.1018x over previous
//
#include <hip/hip_runtime.h>

// ---------------- CSR construction ----------------

__global__ void zero_i32(int* __restrict__ p, int n) {
    int i = blockIdx.x * blockDim.x + threadIdx.x;
    if (i < n) p[i] = 0;
}

__global__ void hist_kernel(const int* __restrict__ dst, int* __restrict__ counts, int E) {
    int i = blockIdx.x * blockDim.x + threadIdx.x;
    if (i < E) atomicAdd(&counts[dst[i]], 1);
}

// single-workgroup scan: shfl wave-scan + 16-partial wave-scan, ~3 barriers/chunk
__global__ void scan_kernel(const int* __restrict__ counts, int* __restrict__ rowptr, int n) {
    __shared__ int wsum[16];
    __shared__ int carry_s;
    const int tid = threadIdx.x;          // blockDim.x == 1024
    const int lane = tid & 63;
    const int wv = tid >> 6;
    if (tid == 0) carry_s = 0;
    __syncthreads();
    int final_total = 0;
    for (int base = 0; base < n; base += 1024) {
        int i = base + tid;
        int v = (i < n) ? counts[i] : 0;
        int x = v;                         // inclusive wave scan
#pragma unroll
        for (int off = 1; off < 64; off <<= 1) {
            int t = __shfl_up(x, off);
            if (lane >= off) x += t;
        }
        if (lane == 63) wsum[wv] = x;
        __syncthreads();
        int carry = carry_s;               // snapshot before anyone updates
        if (tid < 16) {
            int y = wsum[tid];
#pragma unroll
            for (int off = 1; off < 16; off <<= 1) {
                int t = __shfl_up(y, off);
                if (tid >= off) y += t;
            }
            wsum[tid] = y;
        }
        __syncthreads();
        int woff = carry + ((wv > 0) ? wsum[wv - 1] : 0);
        if (i < n) rowptr[i] = woff + x - v;   // exclusive
        int total = carry + wsum[15];
        if (tid == 0) { carry_s = total; final_total = total; }
        __syncthreads();                   // protect wsum/carry_s for next chunk
    }
    if (tid == 0) rowptr[n] = final_total;
}

// scatter edges into dst-sorted order; store src/dst per sorted slot directly
__global__ void scatter_kernel(const int* __restrict__ src, const int* __restrict__ dst,
                               const int* __restrict__ rowptr, int* __restrict__ cursor,
                               int* __restrict__ srcs, int* __restrict__ dsts, int E) {
    int i = blockIdx.x * blockDim.x + threadIdx.x;
    if (i < E) {
        int d = dst[i];
        int p = rowptr[d] + atomicAdd(&cursor[d], 1);
        srcs[p] = src[i];
        dsts[p] = d;
    }
}

// ---------------- fused GEMM + el/er projection ----------------
// feat[n][j] = sum_k A'[n][k] * W[k][j],  A' = RELU_IN ? relu(A + bin) : A
// el[n][h] = sum_d feat[n][h][d] * al[h][d]   (same for er)
// blockDim = FOUT/2; each thread owns columns j and j+FOUT/2.
template <int FIN, int FOUT, int D, bool RELU_IN>
__global__ void gemm_att(const float* __restrict__ A, const float* __restrict__ bin,
                         const float* __restrict__ W, const float* __restrict__ al,
                         const float* __restrict__ ar, float* __restrict__ feat,
                         float* __restrict__ el, float* __restrict__ er, int N) {
    constexpr int R = 16;
    constexpr int H = FOUT / D;
    constexpr int T = FOUT / 2;
    __shared__ __align__(16) float As[FIN][R + 4];   // transposed A tile, padded
    const int j = threadIdx.x;            // 0..T-1
    const int h0 = j / D;
    const int h1 = (j + T) / D;
    const float alv0 = al[j],     arv0 = ar[j];
    const float alv1 = al[j + T], arv1 = ar[j + T];
    const int row0 = blockIdx.x * R;

    for (int idx = threadIdx.x; idx < R * FIN; idx += T) {
        int r = idx / FIN, k = idx % FIN;
        int rr = row0 + r;
        float v = 0.f;
        if (rr < N) {
            v = A[(size_t)rr * FIN + k];
            if constexpr (RELU_IN) { v += bin[k]; v = fmaxf(v, 0.f); }
        }
        As[k][r] = v;
    }
    __syncthreads();

    float acc0[R], acc1[R];
#pragma unroll
    for (int r = 0; r < R; r++) { acc0[r] = 0.f; acc1[r] = 0.f; }

    for (int k = 0; k < FIN; k++) {
        float w0 = W[(size_t)k * FOUT + j];
        float w1 = W[(size_t)k * FOUT + j + T];
        const float4* ap = reinterpret_cast<const float4*>(&As[k][0]);
        float av[16];
        *reinterpret_cast<float4*>(&av[0])  = ap[0];
        *reinterpret_cast<float4*>(&av[4])  = ap[1];
        *reinterpret_cast<float4*>(&av[8])  = ap[2];
        *reinterpret_cast<float4*>(&av[12]) = ap[3];
#pragma unroll
        for (int r = 0; r < R; r++) {
            acc0[r] += av[r] * w0;
            acc1[r] += av[r] * w1;
        }
    }

#pragma unroll
    for (int r = 0; r < R; r++) {
        int rr = row0 + r;
        if (rr >= N) break;               // uniform across block
        float v0 = acc0[r], v1 = acc1[r];
        feat[(size_t)rr * FOUT + j] = v0;
        feat[(size_t)rr * FOUT + j + T] = v1;
        float vl0 = v0 * alv0, vr0 = v0 * arv0;
        float vl1 = v1 * alv1, vr1 = v1 * arv1;
#pragma unroll
        for (int off = D / 2; off >= 1; off >>= 1) {
            vl0 += __shfl_xor(vl0, off);
            vr0 += __shfl_xor(vr0, off);
            vl1 += __shfl_xor(vl1, off);
            vr1 += __shfl_xor(vr1, off);
        }
        if ((j % D) == 0) {
            el[(size_t)rr * H + h0] = vl0;
            er[(size_t)rr * H + h0] = vr0;
            el[(size_t)rr * H + h1] = vl1;
            er[(size_t)rr * H + h1] = vr1;
        }
    }
}

// ---------------- edge-parallel attention logits ----------------
// xbuf[i][h] = leaky_relu(el[srcs[i]][h] + er[dsts[i]][h]),  H == 4 (float4)
__global__ void edge_x_kernel(const int* __restrict__ srcs, const int* __restrict__ dsts,
                              const float4* __restrict__ el, const float4* __restrict__ er,
                              float4* __restrict__ xbuf, int E) {
    int i = blockIdx.x * blockDim.x + threadIdx.x;
    if (i >= E) return;
    int u = srcs[i], d = dsts[i];
    float4 l = el[u], r = er[d];
    float4 x;
    x.x = l.x + r.x; x.x = x.x > 0.f ? x.x : 0.2f * x.x;
    x.y = l.y + r.y; x.y = x.y > 0.f ? x.y : 0.2f * x.y;
    x.z = l.z + r.z; x.z = x.z > 0.f ? x.z : 0.2f * x.z;
    x.w = l.w + r.w; x.w = x.w > 0.f ? x.w : 0.2f * x.w;
    xbuf[i] = x;
}

// ---------------- per-dst-node edge softmax + aggregation ----------------
// Each thread owns 4 contiguous channels (float4). TPN = HD/4 threads per node;
// 256-thread blocks pack NPB = 256/TPN nodes. H == 4.
template <int H, int D>
__global__ void agg_kernel(const float4* __restrict__ feat4, const float* __restrict__ xbuf,
                           const int* __restrict__ srcs, const int* __restrict__ rowptr,
                           float4* __restrict__ out4, int N) {
    constexpr int HD = H * D;
    constexpr int TPN = HD / 4;          // 32 (HD=128) or 64 (HD=256)
    constexpr int NPB = 256 / TPN;       // 8 or 4
    constexpr int GSZ = D / 4;           // lanes per head group: 8 or 16
    const int tid = threadIdx.x;
    const int ln = tid % TPN;            // lane within node
    const int node = blockIdx.x * NPB + tid / TPN;
    if (node >= N) return;
    const int h = ln / GSZ;              // head of this thread's 4 channels
    const int g = ln % GSZ;              // lane within head group
    const int beg = rowptr[node], end = rowptr[node + 1];

    // phase 1: edge-parallel online softmax stats (per head), GSZ-lane stride
    float m = -3.4e38f, s = 0.f;
    for (int i = beg + g; i < end; i += GSZ) {
        float x = xbuf[(size_t)i * H + h];
        float mn = fmaxf(m, x);
        s = s * __expf(m - mn) + __expf(x - mn);
        m = mn;
    }
#pragma unroll
    for (int off = GSZ / 2; off >= 1; off >>= 1) {
        float m2 = __shfl_xor(m, off);
        float s2 = __shfl_xor(s, off);
        float mn = fmaxf(m, m2);
        s = s * __expf(m - mn) + s2 * __expf(m2 - mn);
        m = mn;
    }
    const float inv = (s > 0.f) ? 1.f / s : 0.f;

    // phase 2: weighted gather, unroll x4 for memory-level parallelism
    float4 acc0 = {0,0,0,0}, acc1 = {0,0,0,0}, acc2 = {0,0,0,0}, acc3 = {0,0,0,0};
    int i = beg;
    for (; i + 4 <= end; i += 4) {
        int u0 = srcs[i], u1 = srcs[i + 1], u2 = srcs[i + 2], u3 = srcs[i + 3];
        float x0 = xbuf[(size_t)i * H + h];
        float x1 = xbuf[(size_t)(i + 1) * H + h];
        float x2 = xbuf[(size_t)(i + 2) * H + h];
        float x3 = xbuf[(size_t)(i + 3) * H + h];
        float4 f0 = feat4[(size_t)u0 * TPN + ln];
        float4 f1 = feat4[(size_t)u1 * TPN + ln];
        float4 f2 = feat4[(size_t)u2 * TPN + ln];
        float4 f3 = feat4[(size_t)u3 * TPN + ln];
        float w0 = __expf(x0 - m), w1 = __expf(x1 - m);
        float w2 = __expf(x2 - m), w3 = __expf(x3 - m);
        acc0.x += w0 * f0.x; acc0.y += w0 * f0.y; acc0.z += w0 * f0.z; acc0.w += w0 * f0.w;
        acc1.x += w1 * f1.x; acc1.y += w1 * f1.y; acc1.z += w1 * f1.z; acc1.w += w1 * f1.w;
        acc2.x += w2 * f2.x; acc2.y += w2 * f2.y; acc2.z += w2 * f2.z; acc2.w += w2 * f2.w;
        acc3.x += w3 * f3.x; acc3.y += w3 * f3.y; acc3.z += w3 * f3.z; acc3.w += w3 * f3.w;
    }
    for (; i < end; i++) {
        int u = srcs[i];
        float x = xbuf[(size_t)i * H + h];
        float4 f = feat4[(size_t)u * TPN + ln];
        float w = __expf(x - m);
        acc0.x += w * f.x; acc0.y += w * f.y; acc0.z += w * f.z; acc0.w += w * f.w;
    }
    float4 o;
    o.x = ((acc0.x + acc1.x) + (acc2.x + acc3.x)) * inv;
    o.y = ((acc0.y + acc1.y) + (acc2.y + acc3.y)) * inv;
    o.z = ((acc0.z + acc1.z) + (acc2.z + acc3.z)) * inv;
    o.w = ((acc0.w + acc1.w) + (acc2.w + acc3.w)) * inv;
    out4[(size_t)node * TPN + ln] = o;
}

// ---------------- batched-graph mean readout ----------------

__device__ __forceinline__ int lower_bound_i(const int* __restrict__ a, int n, int key) {
    int lo = 0, hi = n;
    while (lo < hi) {
        int mid = (lo + hi) >> 1;
        if (a[mid] < key) lo = mid + 1; else hi = mid;
    }
    return lo;
}

__global__ void readout_partial(const float* __restrict__ agg, const int* __restrict__ gid,
                                float* __restrict__ part, int N, int C, int SL) {
    int g = blockIdx.x / SL, slice = blockIdx.x % SL;
    int c = threadIdx.x;                 // blockDim.x == C
    int start = lower_bound_i(gid, N, g);
    int end = lower_bound_i(gid, N, g + 1);
    float sum = 0.f;
    for (int n = start + slice; n < end; n += SL) sum += agg[(size_t)n * C + c];
    part[((size_t)g * SL + slice) * C + c] = sum;
}

__global__ void readout_final(const float* __restrict__ part, const float* __restrict__ b3,
                              const int* __restrict__ gid, float* __restrict__ out,
                              int N, int C, int SL) {
    int g = blockIdx.x, c = threadIdx.x;
    int start = lower_bound_i(gid, N, g);
    int end = lower_bound_i(gid, N, g + 1);
    int cnt = end - start;
    float s = 0.f;
    for (int k = 0; k < SL; k++) s += part[((size_t)g * SL + k) * C + c];
    out[(size_t)g * C + c] = (cnt > 0) ? s / (float)cnt + b3[c] : 0.f;
}

// ---------------- launch ----------------

extern "C" void kernel_launch(void* const* d_in, const int* in_sizes, int n_in,
                              void* d_out, int out_size, void* d_ws, size_t ws_size,
                              hipStream_t stream) {
    const float* feat0 = (const float*)d_in[0];
    const int* src = (const int*)d_in[1];
    const int* dst = (const int*)d_in[2];
    const int* gid = (const int*)d_in[3];
    const float* W1 = (const float*)d_in[4];
    const float* al1 = (const float*)d_in[5];
    const float* ar1 = (const float*)d_in[6];
    const float* b1 = (const float*)d_in[7];
    const float* W2 = (const float*)d_in[8];
    const float* al2 = (const float*)d_in[9];
    const float* ar2 = (const float*)d_in[10];
    const float* b2 = (const float*)d_in[11];
    const float* W3 = (const float*)d_in[12];
    const float* al3 = (const float*)d_in[13];
    const float* ar3 = (const float*)d_in[14];
    const float* b3 = (const float*)d_in[15];

    const int N = in_sizes[0] / 6;       // 30000
    const int E = in_sizes[1];           // 480000
    const int G = 64;
    const int SL = 8;
    float* out = (float*)d_out;

    char* wsp = (char*)d_ws;
    auto alloc = [&](size_t bytes) -> char* {
        char* p = wsp;
        wsp += (bytes + 255) & ~(size_t)255;
        return p;
    };
    int* counts  = (int*)alloc((size_t)N * 4);
    int* rowptr  = (int*)alloc((size_t)(N + 1) * 4);
    int* cursor  = (int*)alloc((size_t)N * 4);
    int* srcs    = (int*)alloc((size_t)E * 4);
    int* dsts    = (int*)alloc((size_t)E * 4);
    float* xbuf  = (float*)alloc((size_t)E * 4 * 4);
    float* el    = (float*)alloc((size_t)N * 4 * 4);
    float* er    = (float*)alloc((size_t)N * 4 * 4);
    float* featA = (float*)alloc((size_t)N * 256 * 4);
    float* aggB  = (float*)alloc((size_t)N * 256 * 4);
    float* part  = (float*)alloc((size_t)G * SL * 256 * 4);

    // CSR build (dst-sorted edge list with materialized src/dst per slot)
    zero_i32<<<dim3((N + 255) / 256), dim3(256), 0, stream>>>(counts, N);
    zero_i32<<<dim3((N + 255) / 256), dim3(256), 0, stream>>>(cursor, N);
    hist_kernel<<<dim3((E + 255) / 256), dim3(256), 0, stream>>>(dst, counts, E);
    scan_kernel<<<dim3(1), dim3(1024), 0, stream>>>(counts, rowptr, N);
    scatter_kernel<<<dim3((E + 255) / 256), dim3(256), 0, stream>>>(
        src, dst, rowptr, cursor, srcs, dsts, E);

    const int gemmGrid = (N + 15) / 16;
    const int edgeGrid = (E + 255) / 256;

    // layer 1
    gemm_att<6, 128, 32, false><<<dim3(gemmGrid), dim3(64), 0, stream>>>(
        feat0, nullptr, W1, al1, ar1, featA, el, er, N);
    edge_x_kernel<<<dim3(edgeGrid), dim3(256), 0, stream>>>(
        srcs, dsts, (const float4*)el, (const float4*)er, (float4*)xbuf, E);
    agg_kernel<4, 32><<<dim3((N + 7) / 8), dim3(256), 0, stream>>>(
        (const float4*)featA, xbuf, srcs, rowptr, (float4*)aggB, N);

    // layer 2 (relu(prev + b1) fused into A load)
    gemm_att<128, 128, 32, true><<<dim3(gemmGrid), dim3(64), 0, stream>>>(
        aggB, b1, W2, al2, ar2, featA, el, er, N);
    edge_x_kernel<<<dim3(edgeGrid), dim3(256), 0, stream>>>(
        srcs, dsts, (const float4*)el, (const float4*)er, (float4*)xbuf, E);
    agg_kernel<4, 32><<<dim3((N + 7) / 8), dim3(256), 0, stream>>>(
        (const float4*)featA, xbuf, srcs, rowptr, (float4*)aggB, N);

    // layer 3
    gemm_att<128, 256, 64, true><<<dim3(gemmGrid), dim3(128), 0, stream>>>(
        aggB, b2, W3, al3, ar3, featA, el, er, N);
    edge_x_kernel<<<dim3(edgeGrid), dim3(256), 0, stream>>>(
        srcs, dsts, (const float4*)el, (const float4*)er, (float4*)xbuf, E);
    agg_kernel<4, 64><<<dim3((N + 3) / 4), dim3(256), 0, stream>>>(
        (const float4*)featA, xbuf, srcs, rowptr, (float4*)aggB, N);

    // readout: mean over nodes per graph, + b3
    readout_partial<<<dim3(G * SL), dim3(256), 0, stream>>>(aggB, gid, part, N, 256, SL);
    readout_final<<<dim3(G), dim3(256), 0, stream>>>(part, b3, gid, out, N, 256, SL);
}

// Round 4
// 324.501 us; speedup vs baseline: 2.5447x; 1.1924x over previous
//
#include <hip/hip_runtime.h>

typedef _Float16 h4 __attribute__((ext_vector_type(4)));

// ---------------- CSR construction ----------------

__global__ void zero_i32(int* __restrict__ p, int n) {
    int i = blockIdx.x * blockDim.x + threadIdx.x;
    if (i < n) p[i] = 0;
}

__global__ void hist_kernel(const int* __restrict__ dst, int* __restrict__ counts, int E) {
    int i = blockIdx.x * blockDim.x + threadIdx.x;
    if (i < E) atomicAdd(&counts[dst[i]], 1);
}

// multi-block scan: per-block exclusive scan + block sums
__global__ void scan_block(const int* __restrict__ counts, int* __restrict__ rowptr,
                           int* __restrict__ bsum, int n) {
    __shared__ int wsum[16];
    const int tid = threadIdx.x;           // blockDim.x == 1024
    const int lane = tid & 63, wv = tid >> 6;
    const int i = blockIdx.x * 1024 + tid;
    int v = (i < n) ? counts[i] : 0;
    int x = v;
#pragma unroll
    for (int off = 1; off < 64; off <<= 1) {
        int t = __shfl_up(x, off);
        if (lane >= off) x += t;
    }
    if (lane == 63) wsum[wv] = x;
    __syncthreads();
    if (tid < 16) {
        int y = wsum[tid];
#pragma unroll
        for (int off = 1; off < 16; off <<= 1) {
            int t = __shfl_up(y, off);
            if (tid >= off) y += t;
        }
        wsum[tid] = y;
    }
    __syncthreads();
    int woff = (wv > 0) ? wsum[wv - 1] : 0;
    if (i < n) rowptr[i] = woff + x - v;   // block-local exclusive
    if (tid == 0) bsum[blockIdx.x] = wsum[15];
}

// single-wave scan of block sums (nb <= 64); also writes rowptr[n] = total
__global__ void scan_tops(int* __restrict__ bsum, int* __restrict__ rowptr, int nb, int n) {
    const int tid = threadIdx.x;           // blockDim.x == 64
    int v = (tid < nb) ? bsum[tid] : 0;
    int x = v;
#pragma unroll
    for (int off = 1; off < 64; off <<= 1) {
        int t = __shfl_up(x, off);
        if (tid >= off) x += t;
    }
    if (tid < nb) bsum[tid] = x - v;       // exclusive block offsets
    if (tid == 63) rowptr[n] = x;          // grand total
}

__global__ void scan_add(int* __restrict__ rowptr, const int* __restrict__ bsum, int n) {
    int b = blockIdx.x;
    int i = b * 1024 + threadIdx.x;
    if (i < n && b > 0) rowptr[i] += bsum[b];
}

// scatter edges into dst-sorted order; store src/dst per sorted slot directly
__global__ void scatter_kernel(const int* __restrict__ src, const int* __restrict__ dst,
                               const int* __restrict__ rowptr, int* __restrict__ cursor,
                               int* __restrict__ srcs, int* __restrict__ dsts, int E) {
    int i = blockIdx.x * blockDim.x + threadIdx.x;
    if (i < E) {
        int d = dst[i];
        int p = rowptr[d] + atomicAdd(&cursor[d], 1);
        srcs[p] = src[i];
        dsts[p] = d;
    }
}

// ---------------- fused GEMM + el/er projection ----------------
// feat[n][j] = sum_k A'[n][k] * W[k][j],  A' = RELU_IN ? relu(A + bin) : A
// feat stored fp16 (message values only); el/er in fp32 from fp32 accumulators.
// blockDim = FOUT/2; each thread owns columns j and j+FOUT/2.
template <int FIN, int FOUT, int D, bool RELU_IN>
__global__ void gemm_att(const float* __restrict__ A, const float* __restrict__ bin,
                         const float* __restrict__ W, const float* __restrict__ al,
                         const float* __restrict__ ar, _Float16* __restrict__ feat,
                         float* __restrict__ el, float* __restrict__ er, int N) {
    constexpr int R = 16;
    constexpr int H = FOUT / D;
    constexpr int T = FOUT / 2;
    __shared__ __align__(16) float As[FIN][R + 4];   // transposed A tile, padded
    const int j = threadIdx.x;            // 0..T-1
    const int h0 = j / D;
    const int h1 = (j + T) / D;
    const float alv0 = al[j],     arv0 = ar[j];
    const float alv1 = al[j + T], arv1 = ar[j + T];
    const int row0 = blockIdx.x * R;

    for (int idx = threadIdx.x; idx < R * FIN; idx += T) {
        int r = idx / FIN, k = idx % FIN;
        int rr = row0 + r;
        float v = 0.f;
        if (rr < N) {
            v = A[(size_t)rr * FIN + k];
            if constexpr (RELU_IN) { v += bin[k]; v = fmaxf(v, 0.f); }
        }
        As[k][r] = v;
    }
    __syncthreads();

    float acc0[R], acc1[R];
#pragma unroll
    for (int r = 0; r < R; r++) { acc0[r] = 0.f; acc1[r] = 0.f; }

    for (int k = 0; k < FIN; k++) {
        float w0 = W[(size_t)k * FOUT + j];
        float w1 = W[(size_t)k * FOUT + j + T];
        const float4* ap = reinterpret_cast<const float4*>(&As[k][0]);
        float av[16];
        *reinterpret_cast<float4*>(&av[0])  = ap[0];
        *reinterpret_cast<float4*>(&av[4])  = ap[1];
        *reinterpret_cast<float4*>(&av[8])  = ap[2];
        *reinterpret_cast<float4*>(&av[12]) = ap[3];
#pragma unroll
        for (int r = 0; r < R; r++) {
            acc0[r] += av[r] * w0;
            acc1[r] += av[r] * w1;
        }
    }

#pragma unroll
    for (int r = 0; r < R; r++) {
        int rr = row0 + r;
        if (rr >= N) break;               // uniform across block
        float v0 = acc0[r], v1 = acc1[r];
        feat[(size_t)rr * FOUT + j] = (_Float16)v0;
        feat[(size_t)rr * FOUT + j + T] = (_Float16)v1;
        float vl0 = v0 * alv0, vr0 = v0 * arv0;
        float vl1 = v1 * alv1, vr1 = v1 * arv1;
#pragma unroll
        for (int off = D / 2; off >= 1; off >>= 1) {
            vl0 += __shfl_xor(vl0, off);
            vr0 += __shfl_xor(vr0, off);
            vl1 += __shfl_xor(vl1, off);
            vr1 += __shfl_xor(vr1, off);
        }
        if ((j % D) == 0) {
            el[(size_t)rr * H + h0] = vl0;
            er[(size_t)rr * H + h0] = vr0;
            el[(size_t)rr * H + h1] = vl1;
            er[(size_t)rr * H + h1] = vr1;
        }
    }
}

// ---------------- edge-parallel attention logits ----------------
// xbuf[i][h] = leaky_relu(el[srcs[i]][h] + er[dsts[i]][h]),  H == 4 (float4)
__global__ void edge_x_kernel(const int* __restrict__ srcs, const int* __restrict__ dsts,
                              const float4* __restrict__ el, const float4* __restrict__ er,
                              float4* __restrict__ xbuf, int E) {
    int i = blockIdx.x * blockDim.x + threadIdx.x;
    if (i >= E) return;
    int u = srcs[i], d = dsts[i];
    float4 l = el[u], r = er[d];
    float4 x;
    x.x = l.x + r.x; x.x = x.x > 0.f ? x.x : 0.2f * x.x;
    x.y = l.y + r.y; x.y = x.y > 0.f ? x.y : 0.2f * x.y;
    x.z = l.z + r.z; x.z = x.z > 0.f ? x.z : 0.2f * x.z;
    x.w = l.w + r.w; x.w = x.w > 0.f ? x.w : 0.2f * x.w;
    xbuf[i] = x;
}

// ---------------- per-dst-node edge softmax + aggregation ----------------
// Each thread owns 4 contiguous channels (h4 = 4x fp16, 8B loads).
// TPN = HD/4 threads per node; 256-thread blocks pack NPB nodes. H == 4.
// Phase 1: all TPN lanes stride edges with coalesced float4 loads, online m/s
// for all 4 heads per lane, then one TPN-wide butterfly combine.
template <int H, int D>
__global__ void agg_kernel(const h4* __restrict__ featH, const float4* __restrict__ xbuf4,
                           const int* __restrict__ srcs, const int* __restrict__ rowptr,
                           float4* __restrict__ out4, int N) {
    constexpr int HD = H * D;
    constexpr int TPN = HD / 4;          // 32 (HD=128) or 64 (HD=256)
    constexpr int NPB = 256 / TPN;       // 8 or 4
    const int tid = threadIdx.x;
    const int ln = tid % TPN;            // lane within node
    const int node = blockIdx.x * NPB + tid / TPN;
    if (node >= N) return;
    const int h = (ln * 4) / D;          // head of this thread's 4 channels
    const int beg = rowptr[node], end = rowptr[node + 1];

    // phase 1: online softmax stats for all 4 heads, TPN-lane stride
    float mx = -3.4e38f, my = -3.4e38f, mz = -3.4e38f, mw = -3.4e38f;
    float sx = 0.f, sy = 0.f, sz = 0.f, sw = 0.f;
    for (int i = beg + ln; i < end; i += TPN) {
        float4 x = xbuf4[i];
        float t;
        t = fmaxf(mx, x.x); sx = sx * __expf(mx - t) + __expf(x.x - t); mx = t;
        t = fmaxf(my, x.y); sy = sy * __expf(my - t) + __expf(x.y - t); my = t;
        t = fmaxf(mz, x.z); sz = sz * __expf(mz - t) + __expf(x.z - t); mz = t;
        t = fmaxf(mw, x.w); sw = sw * __expf(mw - t) + __expf(x.w - t); mw = t;
    }
#pragma unroll
    for (int off = TPN / 2; off >= 1; off >>= 1) {
        float m2, s2, t;
        m2 = __shfl_xor(mx, off); s2 = __shfl_xor(sx, off);
        t = fmaxf(mx, m2); sx = sx * __expf(mx - t) + s2 * __expf(m2 - t); mx = t;
        m2 = __shfl_xor(my, off); s2 = __shfl_xor(sy, off);
        t = fmaxf(my, m2); sy = sy * __expf(my - t) + s2 * __expf(m2 - t); my = t;
        m2 = __shfl_xor(mz, off); s2 = __shfl_xor(sz, off);
        t = fmaxf(mz, m2); sz = sz * __expf(mz - t) + s2 * __expf(m2 - t); mz = t;
        m2 = __shfl_xor(mw, off); s2 = __shfl_xor(sw, off);
        t = fmaxf(mw, m2); sw = sw * __expf(mw - t) + s2 * __expf(m2 - t); mw = t;
    }
    const float m = (h == 0) ? mx : (h == 1) ? my : (h == 2) ? mz : mw;
    const float s = (h == 0) ? sx : (h == 1) ? sy : (h == 2) ? sz : sw;
    const float inv = (s > 0.f) ? 1.f / s : 0.f;

    // phase 2: weighted gather (fp16 messages), unroll x4 for MLP
    const float* xb = (const float*)xbuf4;
    float4 a0 = {0,0,0,0}, a1 = {0,0,0,0}, a2 = {0,0,0,0}, a3 = {0,0,0,0};
    int i = beg;
    for (; i + 4 <= end; i += 4) {
        int u0 = srcs[i], u1 = srcs[i + 1], u2 = srcs[i + 2], u3 = srcs[i + 3];
        float x0 = xb[(size_t)i * 4 + h];
        float x1 = xb[(size_t)(i + 1) * 4 + h];
        float x2 = xb[(size_t)(i + 2) * 4 + h];
        float x3 = xb[(size_t)(i + 3) * 4 + h];
        h4 f0 = featH[(size_t)u0 * TPN + ln];
        h4 f1 = featH[(size_t)u1 * TPN + ln];
        h4 f2 = featH[(size_t)u2 * TPN + ln];
        h4 f3 = featH[(size_t)u3 * TPN + ln];
        float w0 = __expf(x0 - m), w1 = __expf(x1 - m);
        float w2 = __expf(x2 - m), w3 = __expf(x3 - m);
        a0.x += w0 * (float)f0[0]; a0.y += w0 * (float)f0[1];
        a0.z += w0 * (float)f0[2]; a0.w += w0 * (float)f0[3];
        a1.x += w1 * (float)f1[0]; a1.y += w1 * (float)f1[1];
        a1.z += w1 * (float)f1[2]; a1.w += w1 * (float)f1[3];
        a2.x += w2 * (float)f2[0]; a2.y += w2 * (float)f2[1];
        a2.z += w2 * (float)f2[2]; a2.w += w2 * (float)f2[3];
        a3.x += w3 * (float)f3[0]; a3.y += w3 * (float)f3[1];
        a3.z += w3 * (float)f3[2]; a3.w += w3 * (float)f3[3];
    }
    for (; i < end; i++) {
        int u = srcs[i];
        float x = xb[(size_t)i * 4 + h];
        h4 f = featH[(size_t)u * TPN + ln];
        float w = __expf(x - m);
        a0.x += w * (float)f[0]; a0.y += w * (float)f[1];
        a0.z += w * (float)f[2]; a0.w += w * (float)f[3];
    }
    float4 o;
    o.x = ((a0.x + a1.x) + (a2.x + a3.x)) * inv;
    o.y = ((a0.y + a1.y) + (a2.y + a3.y)) * inv;
    o.z = ((a0.z + a1.z) + (a2.z + a3.z)) * inv;
    o.w = ((a0.w + a1.w) + (a2.w + a3.w)) * inv;
    out4[(size_t)node * TPN + ln] = o;
}

// ---------------- batched-graph mean readout ----------------

__device__ __forceinline__ int lower_bound_i(const int* __restrict__ a, int n, int key) {
    int lo = 0, hi = n;
    while (lo < hi) {
        int mid = (lo + hi) >> 1;
        if (a[mid] < key) lo = mid + 1; else hi = mid;
    }
    return lo;
}

__global__ void readout_partial(const float* __restrict__ agg, const int* __restrict__ gid,
                                float* __restrict__ part, int N, int C, int SL) {
    int g = blockIdx.x / SL, slice = blockIdx.x % SL;
    int c = threadIdx.x;                 // blockDim.x == C
    int start = lower_bound_i(gid, N, g);
    int end = lower_bound_i(gid, N, g + 1);
    float sum = 0.f;
    for (int n = start + slice; n < end; n += SL) sum += agg[(size_t)n * C + c];
    part[((size_t)g * SL + slice) * C + c] = sum;
}

__global__ void readout_final(const float* __restrict__ part, const float* __restrict__ b3,
                              const int* __restrict__ gid, float* __restrict__ out,
                              int N, int C, int SL) {
    int g = blockIdx.x, c = threadIdx.x;
    int start = lower_bound_i(gid, N, g);
    int end = lower_bound_i(gid, N, g + 1);
    int cnt = end - start;
    float s = 0.f;
    for (int k = 0; k < SL; k++) s += part[((size_t)g * SL + k) * C + c];
    out[(size_t)g * C + c] = (cnt > 0) ? s / (float)cnt + b3[c] : 0.f;
}

// ---------------- launch ----------------

extern "C" void kernel_launch(void* const* d_in, const int* in_sizes, int n_in,
                              void* d_out, int out_size, void* d_ws, size_t ws_size,
                              hipStream_t stream) {
    const float* feat0 = (const float*)d_in[0];
    const int* src = (const int*)d_in[1];
    const int* dst = (const int*)d_in[2];
    const int* gid = (const int*)d_in[3];
    const float* W1 = (const float*)d_in[4];
    const float* al1 = (const float*)d_in[5];
    const float* ar1 = (const float*)d_in[6];
    const float* b1 = (const float*)d_in[7];
    const float* W2 = (const float*)d_in[8];
    const float* al2 = (const float*)d_in[9];
    const float* ar2 = (const float*)d_in[10];
    const float* b2 = (const float*)d_in[11];
    const float* W3 = (const float*)d_in[12];
    const float* al3 = (const float*)d_in[13];
    const float* ar3 = (const float*)d_in[14];
    const float* b3 = (const float*)d_in[15];

    const int N = in_sizes[0] / 6;       // 30000
    const int E = in_sizes[1];           // 480000
    const int G = 64;
    const int SL = 8;
    float* out = (float*)d_out;

    char* wsp = (char*)d_ws;
    auto alloc = [&](size_t bytes) -> char* {
        char* p = wsp;
        wsp += (bytes + 255) & ~(size_t)255;
        return p;
    };
    int* counts   = (int*)alloc((size_t)N * 4);
    int* rowptr   = (int*)alloc((size_t)(N + 1) * 4);
    int* cursor   = (int*)alloc((size_t)N * 4);
    int* bsum     = (int*)alloc(64 * 4);
    int* srcs     = (int*)alloc((size_t)E * 4);
    int* dsts     = (int*)alloc((size_t)E * 4);
    float* xbuf   = (float*)alloc((size_t)E * 4 * 4);
    float* el     = (float*)alloc((size_t)N * 4 * 4);
    float* er     = (float*)alloc((size_t)N * 4 * 4);
    _Float16* featH = (_Float16*)alloc((size_t)N * 256 * 2);
    float* aggB   = (float*)alloc((size_t)N * 256 * 4);
    float* part   = (float*)alloc((size_t)G * SL * 256 * 4);

    // CSR build (dst-sorted edge list with materialized src/dst per slot)
    const int nb = (N + 1023) / 1024;
    const int zspan = (int)(((char*)bsum - (char*)counts) / 4) + 64;  // counts..bsum
    zero_i32<<<dim3((zspan + 255) / 256), dim3(256), 0, stream>>>(counts, zspan);
    hist_kernel<<<dim3((E + 255) / 256), dim3(256), 0, stream>>>(dst, counts, E);
    scan_block<<<dim3(nb), dim3(1024), 0, stream>>>(counts, rowptr, bsum, N);
    scan_tops<<<dim3(1), dim3(64), 0, stream>>>(bsum, rowptr, nb, N);
    scan_add<<<dim3(nb), dim3(1024), 0, stream>>>(rowptr, bsum, N);
    scatter_kernel<<<dim3((E + 255) / 256), dim3(256), 0, stream>>>(
        src, dst, rowptr, cursor, srcs, dsts, E);

    const int gemmGrid = (N + 15) / 16;
    const int edgeGrid = (E + 255) / 256;

    // layer 1
    gemm_att<6, 128, 32, false><<<dim3(gemmGrid), dim3(64), 0, stream>>>(
        feat0, nullptr, W1, al1, ar1, featH, el, er, N);
    edge_x_kernel<<<dim3(edgeGrid), dim3(256), 0, stream>>>(
        srcs, dsts, (const float4*)el, (const float4*)er, (float4*)xbuf, E);
    agg_kernel<4, 32><<<dim3((N + 7) / 8), dim3(256), 0, stream>>>(
        (const h4*)featH, (const float4*)xbuf, srcs, rowptr, (float4*)aggB, N);

    // layer 2 (relu(prev + b1) fused into A load)
    gemm_att<128, 128, 32, true><<<dim3(gemmGrid), dim3(64), 0, stream>>>(
        aggB, b1, W2, al2, ar2, featH, el, er, N);
    edge_x_kernel<<<dim3(edgeGrid), dim3(256), 0, stream>>>(
        srcs, dsts, (const float4*)el, (const float4*)er, (float4*)xbuf, E);
    agg_kernel<4, 32><<<dim3((N + 7) / 8), dim3(256), 0, stream>>>(
        (const h4*)featH, (const float4*)xbuf, srcs, rowptr, (float4*)aggB, N);

    // layer 3
    gemm_att<128, 256, 64, true><<<dim3(gemmGrid), dim3(128), 0, stream>>>(
        aggB, b2, W3, al3, ar3, featH, el, er, N);
    edge_x_kernel<<<dim3(edgeGrid), dim3(256), 0, stream>>>(
        srcs, dsts, (const float4*)el, (const float4*)er, (float4*)xbuf, E);
    agg_kernel<4, 64><<<dim3((N + 3) / 4), dim3(256), 0, stream>>>(
        (const h4*)featH, (const float4*)xbuf, srcs, rowptr, (float4*)aggB, N);

    // readout: mean over nodes per graph, + b3
    readout_partial<<<dim3(G * SL), dim3(256), 0, stream>>>(aggB, gid, part, N, 256, SL);
    readout_final<<<dim3(G), dim3(256), 0, stream>>>(part, b3, gid, out, N, 256, SL);
}

// Round 5
// 323.428 us; speedup vs baseline: 2.5531x; 1.0033x over previous
//
#include <hip/hip_runtime.h>

typedef _Float16 h4 __attribute__((ext_vector_type(4)));

// ---------------- CSR construction ----------------

__global__ void zero_i32(int* __restrict__ p, int n) {
    int i = blockIdx.x * blockDim.x + threadIdx.x;
    if (i < n) p[i] = 0;
}

__global__ void hist_kernel(const int* __restrict__ dst, int* __restrict__ counts, int E) {
    int i = blockIdx.x * blockDim.x + threadIdx.x;
    if (i < E) atomicAdd(&counts[dst[i]], 1);
}

// multi-block scan: per-block exclusive scan + block sums
__global__ void scan_block(const int* __restrict__ counts, int* __restrict__ rowptr,
                           int* __restrict__ bsum, int n) {
    __shared__ int wsum[16];
    const int tid = threadIdx.x;           // blockDim.x == 1024
    const int lane = tid & 63, wv = tid >> 6;
    const int i = blockIdx.x * 1024 + tid;
    int v = (i < n) ? counts[i] : 0;
    int x = v;
#pragma unroll
    for (int off = 1; off < 64; off <<= 1) {
        int t = __shfl_up(x, off);
        if (lane >= off) x += t;
    }
    if (lane == 63) wsum[wv] = x;
    __syncthreads();
    if (tid < 16) {
        int y = wsum[tid];
#pragma unroll
        for (int off = 1; off < 16; off <<= 1) {
            int t = __shfl_up(y, off);
            if (tid >= off) y += t;
        }
        wsum[tid] = y;
    }
    __syncthreads();
    int woff = (wv > 0) ? wsum[wv - 1] : 0;
    if (i < n) rowptr[i] = woff + x - v;   // block-local exclusive
    if (tid == 0) bsum[blockIdx.x] = wsum[15];
}

// single-wave scan of block sums (nb <= 64); also writes rowptr[n] = total
__global__ void scan_tops(int* __restrict__ bsum, int* __restrict__ rowptr, int nb, int n) {
    const int tid = threadIdx.x;           // blockDim.x == 64
    int v = (tid < nb) ? bsum[tid] : 0;
    int x = v;
#pragma unroll
    for (int off = 1; off < 64; off <<= 1) {
        int t = __shfl_up(x, off);
        if (tid >= off) x += t;
    }
    if (tid < nb) bsum[tid] = x - v;       // exclusive block offsets
    if (tid == 63) rowptr[n] = x;          // grand total
}

__global__ void scan_add(int* __restrict__ rowptr, const int* __restrict__ bsum, int n) {
    int b = blockIdx.x;
    int i = b * 1024 + threadIdx.x;
    if (i < n && b > 0) rowptr[i] += bsum[b];
}

// scatter edges into dst-sorted order; store src/dst per sorted slot directly
__global__ void scatter_kernel(const int* __restrict__ src, const int* __restrict__ dst,
                               const int* __restrict__ rowptr, int* __restrict__ cursor,
                               int* __restrict__ srcs, int* __restrict__ dsts, int E) {
    int i = blockIdx.x * blockDim.x + threadIdx.x;
    if (i < E) {
        int d = dst[i];
        int p = rowptr[d] + atomicAdd(&cursor[d], 1);
        srcs[p] = src[i];
        dsts[p] = d;
    }
}

// ---------------- layer-1 fused GEMM + el/er (tiny FIN=6) ----------------
template <int FIN, int FOUT, int D, bool RELU_IN>
__global__ void gemm_att(const float* __restrict__ A, const float* __restrict__ bin,
                         const float* __restrict__ W, const float* __restrict__ al,
                         const float* __restrict__ ar, _Float16* __restrict__ feat,
                         float* __restrict__ el, float* __restrict__ er, int N) {
    constexpr int R = 16;
    constexpr int H = FOUT / D;
    constexpr int T = FOUT / 2;
    __shared__ __align__(16) float As[FIN][R + 4];   // transposed A tile, padded
    const int j = threadIdx.x;            // 0..T-1
    const int h0 = j / D;
    const int h1 = (j + T) / D;
    const float alv0 = al[j],     arv0 = ar[j];
    const float alv1 = al[j + T], arv1 = ar[j + T];
    const int row0 = blockIdx.x * R;

    for (int idx = threadIdx.x; idx < R * FIN; idx += T) {
        int r = idx / FIN, k = idx % FIN;
        int rr = row0 + r;
        float v = 0.f;
        if (rr < N) {
            v = A[(size_t)rr * FIN + k];
            if constexpr (RELU_IN) { v += bin[k]; v = fmaxf(v, 0.f); }
        }
        As[k][r] = v;
    }
    __syncthreads();

    float acc0[R], acc1[R];
#pragma unroll
    for (int r = 0; r < R; r++) { acc0[r] = 0.f; acc1[r] = 0.f; }

    for (int k = 0; k < FIN; k++) {
        float w0 = W[(size_t)k * FOUT + j];
        float w1 = W[(size_t)k * FOUT + j + T];
        const float4* ap = reinterpret_cast<const float4*>(&As[k][0]);
        float av[16];
        *reinterpret_cast<float4*>(&av[0])  = ap[0];
        *reinterpret_cast<float4*>(&av[4])  = ap[1];
        *reinterpret_cast<float4*>(&av[8])  = ap[2];
        *reinterpret_cast<float4*>(&av[12]) = ap[3];
#pragma unroll
        for (int r = 0; r < R; r++) {
            acc0[r] += av[r] * w0;
            acc1[r] += av[r] * w1;
        }
    }

#pragma unroll
    for (int r = 0; r < R; r++) {
        int rr = row0 + r;
        if (rr >= N) break;               // uniform across block
        float v0 = acc0[r], v1 = acc1[r];
        feat[(size_t)rr * FOUT + j] = (_Float16)v0;
        feat[(size_t)rr * FOUT + j + T] = (_Float16)v1;
        float vl0 = v0 * alv0, vr0 = v0 * arv0;
        float vl1 = v1 * alv1, vr1 = v1 * arv1;
#pragma unroll
        for (int off = D / 2; off >= 1; off >>= 1) {
            vl0 += __shfl_xor(vl0, off);
            vr0 += __shfl_xor(vr0, off);
            vl1 += __shfl_xor(vl1, off);
            vr1 += __shfl_xor(vr1, off);
        }
        if ((j % D) == 0) {
            el[(size_t)rr * H + h0] = vl0;
            er[(size_t)rr * H + h0] = vr0;
            el[(size_t)rr * H + h1] = vl1;
            er[(size_t)rr * H + h1] = vr1;
        }
    }
}

// ---------------- layers 2/3: register-tiled GEMM + el/er, C=4 cols/thread ----
// 64-thread (1-wave) blocks. COLT = FOUT/4 column-threads; RG = 64/COLT row
// groups of 16 rows. Thread owns 4 adjacent columns (float4 W loads) x 16 rows.
// k-loop unrolled x2 with double-buffered A fragments + W prefetch.
template <int FIN, int FOUT, int D, bool RELU_IN>
__global__ __launch_bounds__(64)
void gemm_att4(const float* __restrict__ A, const float* __restrict__ bin,
               const float* __restrict__ W, const float* __restrict__ al,
               const float* __restrict__ ar, _Float16* __restrict__ feat,
               float* __restrict__ el, float* __restrict__ er, int N) {
    constexpr int COLT = FOUT / 4;       // 64 (FOUT=256) or 32 (FOUT=128)
    constexpr int RG   = 64 / COLT;      // 1 or 2 row groups
    constexpr int RB   = RG * 16;        // rows per block
    constexpr int H    = FOUT / D;
    constexpr int GL   = D / 4;          // lanes per head group (8 or 16)
    constexpr int LROW = RB + 4;
    __shared__ __align__(16) float As[FIN][LROW];
    const int tid = threadIdx.x;
    const int jt = tid % COLT;
    const int rg = tid / COLT;
    const int row0 = blockIdx.x * RB;
    const int h = jt / GL;

    // fill LDS transposed: float4 global reads, 4 scalar LDS writes
    constexpr int NV = RB * FIN / 4;
    for (int v = tid; v < NV; v += 64) {
        int r  = v / (FIN / 4);
        int kv = (v % (FIN / 4)) * 4;
        int rr = row0 + r;
        float4 x = {0.f, 0.f, 0.f, 0.f};
        if (rr < N) {
            x = *reinterpret_cast<const float4*>(&A[(size_t)rr * FIN + kv]);
            if constexpr (RELU_IN) {
                float4 bv = *reinterpret_cast<const float4*>(&bin[kv]);
                x.x = fmaxf(x.x + bv.x, 0.f);
                x.y = fmaxf(x.y + bv.y, 0.f);
                x.z = fmaxf(x.z + bv.z, 0.f);
                x.w = fmaxf(x.w + bv.w, 0.f);
            }
        }
        As[kv][r] = x.x; As[kv + 1][r] = x.y; As[kv + 2][r] = x.z; As[kv + 3][r] = x.w;
    }
    __syncthreads();

    float4 acc[16];
#pragma unroll
    for (int r = 0; r < 16; r++) acc[r] = make_float4(0.f, 0.f, 0.f, 0.f);

    const float4* Wv = reinterpret_cast<const float4*>(W);
    constexpr int WS = FOUT / 4;
    float4 wA, wB;
    float4 aA[4], aB[4];
    auto loadA = [&](float4* dst, int kk) {
        const float4* ap = reinterpret_cast<const float4*>(&As[kk][rg * 16]);
        dst[0] = ap[0]; dst[1] = ap[1]; dst[2] = ap[2]; dst[3] = ap[3];
    };
    wA = Wv[jt];
    loadA(aA, 0);
    for (int k = 0; k < FIN; k += 2) {
        int k1 = k + 1;
        int k2 = (k + 2 < FIN) ? k + 2 : FIN - 1;   // clamped prefetch
        wB = Wv[(size_t)k1 * WS + jt];
        loadA(aB, k1);
        {
            const float* af = reinterpret_cast<const float*>(aA);
#pragma unroll
            for (int r = 0; r < 16; r++) {
                float av = af[r];
                acc[r].x += av * wA.x; acc[r].y += av * wA.y;
                acc[r].z += av * wA.z; acc[r].w += av * wA.w;
            }
        }
        wA = Wv[(size_t)k2 * WS + jt];
        loadA(aA, k2);
        {
            const float* af = reinterpret_cast<const float*>(aB);
#pragma unroll
            for (int r = 0; r < 16; r++) {
                float av = af[r];
                acc[r].x += av * wB.x; acc[r].y += av * wB.y;
                acc[r].z += av * wB.z; acc[r].w += av * wB.w;
            }
        }
    }

    const float4 al4 = *reinterpret_cast<const float4*>(&al[4 * jt]);
    const float4 ar4 = *reinterpret_cast<const float4*>(&ar[4 * jt]);
#pragma unroll
    for (int r = 0; r < 16; r++) {
        int rr = row0 + rg * 16 + r;
        if (rr < N) {
            float4 v = acc[r];
            h4 fv;
            fv[0] = (_Float16)v.x; fv[1] = (_Float16)v.y;
            fv[2] = (_Float16)v.z; fv[3] = (_Float16)v.w;
            *reinterpret_cast<h4*>(&feat[(size_t)rr * FOUT + 4 * jt]) = fv;
            float vl = v.x * al4.x + v.y * al4.y + v.z * al4.z + v.w * al4.w;
            float vr = v.x * ar4.x + v.y * ar4.y + v.z * ar4.z + v.w * ar4.w;
#pragma unroll
            for (int off = GL / 2; off >= 1; off >>= 1) {
                vl += __shfl_xor(vl, off);
                vr += __shfl_xor(vr, off);
            }
            if ((jt % GL) == 0) {
                el[(size_t)rr * H + h] = vl;
                er[(size_t)rr * H + h] = vr;
            }
        }
    }
}

// ---------------- edge-parallel attention logits ----------------
// xbuf[i][h] = leaky_relu(el[srcs[i]][h] + er[dsts[i]][h]),  H == 4 (float4)
__global__ void edge_x_kernel(const int* __restrict__ srcs, const int* __restrict__ dsts,
                              const float4* __restrict__ el, const float4* __restrict__ er,
                              float4* __restrict__ xbuf, int E) {
    int i = blockIdx.x * blockDim.x + threadIdx.x;
    if (i >= E) return;
    int u = srcs[i], d = dsts[i];
    float4 l = el[u], r = er[d];
    float4 x;
    x.x = l.x + r.x; x.x = x.x > 0.f ? x.x : 0.2f * x.x;
    x.y = l.y + r.y; x.y = x.y > 0.f ? x.y : 0.2f * x.y;
    x.z = l.z + r.z; x.z = x.z > 0.f ? x.z : 0.2f * x.z;
    x.w = l.w + r.w; x.w = x.w > 0.f ? x.w : 0.2f * x.w;
    xbuf[i] = x;
}

// ---------------- per-dst-node edge softmax + aggregation ----------------
template <int H, int D>
__global__ void agg_kernel(const h4* __restrict__ featH, const float4* __restrict__ xbuf4,
                           const int* __restrict__ srcs, const int* __restrict__ rowptr,
                           float4* __restrict__ out4, int N) {
    constexpr int HD = H * D;
    constexpr int TPN = HD / 4;          // 32 (HD=128) or 64 (HD=256)
    constexpr int NPB = 256 / TPN;       // 8 or 4
    const int tid = threadIdx.x;
    const int ln = tid % TPN;            // lane within node
    const int node = blockIdx.x * NPB + tid / TPN;
    if (node >= N) return;
    const int h = (ln * 4) / D;          // head of this thread's 4 channels
    const int beg = rowptr[node], end = rowptr[node + 1];

    // phase 1: online softmax stats for all 4 heads, TPN-lane stride
    float mx = -3.4e38f, my = -3.4e38f, mz = -3.4e38f, mw = -3.4e38f;
    float sx = 0.f, sy = 0.f, sz = 0.f, sw = 0.f;
    for (int i = beg + ln; i < end; i += TPN) {
        float4 x = xbuf4[i];
        float t;
        t = fmaxf(mx, x.x); sx = sx * __expf(mx - t) + __expf(x.x - t); mx = t;
        t = fmaxf(my, x.y); sy = sy * __expf(my - t) + __expf(x.y - t); my = t;
        t = fmaxf(mz, x.z); sz = sz * __expf(mz - t) + __expf(x.z - t); mz = t;
        t = fmaxf(mw, x.w); sw = sw * __expf(mw - t) + __expf(x.w - t); mw = t;
    }
#pragma unroll
    for (int off = TPN / 2; off >= 1; off >>= 1) {
        float m2, s2, t;
        m2 = __shfl_xor(mx, off); s2 = __shfl_xor(sx, off);
        t = fmaxf(mx, m2); sx = sx * __expf(mx - t) + s2 * __expf(m2 - t); mx = t;
        m2 = __shfl_xor(my, off); s2 = __shfl_xor(sy, off);
        t = fmaxf(my, m2); sy = sy * __expf(my - t) + s2 * __expf(m2 - t); my = t;
        m2 = __shfl_xor(mz, off); s2 = __shfl_xor(sz, off);
        t = fmaxf(mz, m2); sz = sz * __expf(mz - t) + s2 * __expf(m2 - t); mz = t;
        m2 = __shfl_xor(mw, off); s2 = __shfl_xor(sw, off);
        t = fmaxf(mw, m2); sw = sw * __expf(mw - t) + s2 * __expf(m2 - t); mw = t;
    }
    const float m = (h == 0) ? mx : (h == 1) ? my : (h == 2) ? mz : mw;
    const float s = (h == 0) ? sx : (h == 1) ? sy : (h == 2) ? sz : sw;
    const float inv = (s > 0.f) ? 1.f / s : 0.f;

    // phase 2: weighted gather (fp16 messages), unroll x4 for MLP
    const float* xb = (const float*)xbuf4;
    float4 a0 = {0,0,0,0}, a1 = {0,0,0,0}, a2 = {0,0,0,0}, a3 = {0,0,0,0};
    int i = beg;
    for (; i + 4 <= end; i += 4) {
        int u0 = srcs[i], u1 = srcs[i + 1], u2 = srcs[i + 2], u3 = srcs[i + 3];
        float x0 = xb[(size_t)i * 4 + h];
        float x1 = xb[(size_t)(i + 1) * 4 + h];
        float x2 = xb[(size_t)(i + 2) * 4 + h];
        float x3 = xb[(size_t)(i + 3) * 4 + h];
        h4 f0 = featH[(size_t)u0 * TPN + ln];
        h4 f1 = featH[(size_t)u1 * TPN + ln];
        h4 f2 = featH[(size_t)u2 * TPN + ln];
        h4 f3 = featH[(size_t)u3 * TPN + ln];
        float w0 = __expf(x0 - m), w1 = __expf(x1 - m);
        float w2 = __expf(x2 - m), w3 = __expf(x3 - m);
        a0.x += w0 * (float)f0[0]; a0.y += w0 * (float)f0[1];
        a0.z += w0 * (float)f0[2]; a0.w += w0 * (float)f0[3];
        a1.x += w1 * (float)f1[0]; a1.y += w1 * (float)f1[1];
        a1.z += w1 * (float)f1[2]; a1.w += w1 * (float)f1[3];
        a2.x += w2 * (float)f2[0]; a2.y += w2 * (float)f2[1];
        a2.z += w2 * (float)f2[2]; a2.w += w2 * (float)f2[3];
        a3.x += w3 * (float)f3[0]; a3.y += w3 * (float)f3[1];
        a3.z += w3 * (float)f3[2]; a3.w += w3 * (float)f3[3];
    }
    for (; i < end; i++) {
        int u = srcs[i];
        float x = xb[(size_t)i * 4 + h];
        h4 f = featH[(size_t)u * TPN + ln];
        float w = __expf(x - m);
        a0.x += w * (float)f[0]; a0.y += w * (float)f[1];
        a0.z += w * (float)f[2]; a0.w += w * (float)f[3];
    }
    float4 o;
    o.x = ((a0.x + a1.x) + (a2.x + a3.x)) * inv;
    o.y = ((a0.y + a1.y) + (a2.y + a3.y)) * inv;
    o.z = ((a0.z + a1.z) + (a2.z + a3.z)) * inv;
    o.w = ((a0.w + a1.w) + (a2.w + a3.w)) * inv;
    out4[(size_t)node * TPN + ln] = o;
}

// ---------------- batched-graph mean readout ----------------

__device__ __forceinline__ int lower_bound_i(const int* __restrict__ a, int n, int key) {
    int lo = 0, hi = n;
    while (lo < hi) {
        int mid = (lo + hi) >> 1;
        if (a[mid] < key) lo = mid + 1; else hi = mid;
    }
    return lo;
}

__global__ void readout_partial(const float* __restrict__ agg, const int* __restrict__ gid,
                                float* __restrict__ part, int N, int C, int SL) {
    int g = blockIdx.x / SL, slice = blockIdx.x % SL;
    int c = threadIdx.x;                 // blockDim.x == C
    int start = lower_bound_i(gid, N, g);
    int end = lower_bound_i(gid, N, g + 1);
    float sum = 0.f;
    for (int n = start + slice; n < end; n += SL) sum += agg[(size_t)n * C + c];
    part[((size_t)g * SL + slice) * C + c] = sum;
}

__global__ void readout_final(const float* __restrict__ part, const float* __restrict__ b3,
                              const int* __restrict__ gid, float* __restrict__ out,
                              int N, int C, int SL) {
    int g = blockIdx.x, c = threadIdx.x;
    int start = lower_bound_i(gid, N, g);
    int end = lower_bound_i(gid, N, g + 1);
    int cnt = end - start;
    float s = 0.f;
    for (int k = 0; k < SL; k++) s += part[((size_t)g * SL + k) * C + c];
    out[(size_t)g * C + c] = (cnt > 0) ? s / (float)cnt + b3[c] : 0.f;
}

// ---------------- launch ----------------

extern "C" void kernel_launch(void* const* d_in, const int* in_sizes, int n_in,
                              void* d_out, int out_size, void* d_ws, size_t ws_size,
                              hipStream_t stream) {
    const float* feat0 = (const float*)d_in[0];
    const int* src = (const int*)d_in[1];
    const int* dst = (const int*)d_in[2];
    const int* gid = (const int*)d_in[3];
    const float* W1 = (const float*)d_in[4];
    const float* al1 = (const float*)d_in[5];
    const float* ar1 = (const float*)d_in[6];
    const float* b1 = (const float*)d_in[7];
    const float* W2 = (const float*)d_in[8];
    const float* al2 = (const float*)d_in[9];
    const float* ar2 = (const float*)d_in[10];
    const float* b2 = (const float*)d_in[11];
    const float* W3 = (const float*)d_in[12];
    const float* al3 = (const float*)d_in[13];
    const float* ar3 = (const float*)d_in[14];
    const float* b3 = (const float*)d_in[15];

    const int N = in_sizes[0] / 6;       // 30000
    const int E = in_sizes[1];           // 480000
    const int G = 64;
    const int SL = 8;
    float* out = (float*)d_out;

    char* wsp = (char*)d_ws;
    auto alloc = [&](size_t bytes) -> char* {
        char* p = wsp;
        wsp += (bytes + 255) & ~(size_t)255;
        return p;
    };
    int* counts   = (int*)alloc((size_t)N * 4);
    int* rowptr   = (int*)alloc((size_t)(N + 1) * 4);
    int* cursor   = (int*)alloc((size_t)N * 4);
    int* bsum     = (int*)alloc(64 * 4);
    int* srcs     = (int*)alloc((size_t)E * 4);
    int* dsts     = (int*)alloc((size_t)E * 4);
    float* xbuf   = (float*)alloc((size_t)E * 4 * 4);
    float* el     = (float*)alloc((size_t)N * 4 * 4);
    float* er     = (float*)alloc((size_t)N * 4 * 4);
    _Float16* featH = (_Float16*)alloc((size_t)N * 256 * 2);
    float* aggB   = (float*)alloc((size_t)N * 256 * 4);
    float* part   = (float*)alloc((size_t)G * SL * 256 * 4);

    // CSR build (dst-sorted edge list with materialized src/dst per slot)
    const int nb = (N + 1023) / 1024;
    const int zspan = (int)(((char*)bsum - (char*)counts) / 4) + 64;  // counts..bsum
    zero_i32<<<dim3((zspan + 255) / 256), dim3(256), 0, stream>>>(counts, zspan);
    hist_kernel<<<dim3((E + 255) / 256), dim3(256), 0, stream>>>(dst, counts, E);
    scan_block<<<dim3(nb), dim3(1024), 0, stream>>>(counts, rowptr, bsum, N);
    scan_tops<<<dim3(1), dim3(64), 0, stream>>>(bsum, rowptr, nb, N);
    scan_add<<<dim3(nb), dim3(1024), 0, stream>>>(rowptr, bsum, N);
    scatter_kernel<<<dim3((E + 255) / 256), dim3(256), 0, stream>>>(
        src, dst, rowptr, cursor, srcs, dsts, E);

    const int edgeGrid = (E + 255) / 256;

    // layer 1
    gemm_att<6, 128, 32, false><<<dim3((N + 15) / 16), dim3(64), 0, stream>>>(
        feat0, nullptr, W1, al1, ar1, featH, el, er, N);
    edge_x_kernel<<<dim3(edgeGrid), dim3(256), 0, stream>>>(
        srcs, dsts, (const float4*)el, (const float4*)er, (float4*)xbuf, E);
    agg_kernel<4, 32><<<dim3((N + 7) / 8), dim3(256), 0, stream>>>(
        (const h4*)featH, (const float4*)xbuf, srcs, rowptr, (float4*)aggB, N);

    // layer 2 (relu(prev + b1) fused into A load); RB=32 rows/block
    gemm_att4<128, 128, 32, true><<<dim3((N + 31) / 32), dim3(64), 0, stream>>>(
        aggB, b1, W2, al2, ar2, featH, el, er, N);
    edge_x_kernel<<<dim3(edgeGrid), dim3(256), 0, stream>>>(
        srcs, dsts, (const float4*)el, (const float4*)er, (float4*)xbuf, E);
    agg_kernel<4, 32><<<dim3((N + 7) / 8), dim3(256), 0, stream>>>(
        (const h4*)featH, (const float4*)xbuf, srcs, rowptr, (float4*)aggB, N);

    // layer 3; RB=16 rows/block
    gemm_att4<128, 256, 64, true><<<dim3((N + 15) / 16), dim3(64), 0, stream>>>(
        aggB, b2, W3, al3, ar3, featH, el, er, N);
    edge_x_kernel<<<dim3(edgeGrid), dim3(256), 0, stream>>>(
        srcs, dsts, (const float4*)el, (const float4*)er, (float4*)xbuf, E);
    agg_kernel<4, 64><<<dim3((N + 3) / 4), dim3(256), 0, stream>>>(
        (const h4*)featH, (const float4*)xbuf, srcs, rowptr, (float4*)aggB, N);

    // readout: mean over nodes per graph, + b3
    readout_partial<<<dim3(G * SL), dim3(256), 0, stream>>>(aggB, gid, part, N, 256, SL);
    readout_final<<<dim3(G), dim3(256), 0, stream>>>(part, b3, gid, out, N, 256, SL);
}

// Round 6
// 262.924 us; speedup vs baseline: 3.1407x; 1.2301x over previous
//
#include <hip/hip_runtime.h>

typedef _Float16 h4 __attribute__((ext_vector_type(4)));
typedef _Float16 h8v __attribute__((ext_vector_type(8)));
typedef float f4v __attribute__((ext_vector_type(4)));

// ---------------- CSR construction ----------------

__global__ void zero_i32(int* __restrict__ p, int n) {
    int i = blockIdx.x * blockDim.x + threadIdx.x;
    if (i < n) p[i] = 0;
}

__global__ void hist_kernel(const int* __restrict__ dst, int* __restrict__ counts, int E) {
    int i = blockIdx.x * blockDim.x + threadIdx.x;
    if (i < E) atomicAdd(&counts[dst[i]], 1);
}

__global__ void scan_block(const int* __restrict__ counts, int* __restrict__ rowptr,
                           int* __restrict__ bsum, int n) {
    __shared__ int wsum[16];
    const int tid = threadIdx.x;           // blockDim.x == 1024
    const int lane = tid & 63, wv = tid >> 6;
    const int i = blockIdx.x * 1024 + tid;
    int v = (i < n) ? counts[i] : 0;
    int x = v;
#pragma unroll
    for (int off = 1; off < 64; off <<= 1) {
        int t = __shfl_up(x, off);
        if (lane >= off) x += t;
    }
    if (lane == 63) wsum[wv] = x;
    __syncthreads();
    if (tid < 16) {
        int y = wsum[tid];
#pragma unroll
        for (int off = 1; off < 16; off <<= 1) {
            int t = __shfl_up(y, off);
            if (tid >= off) y += t;
        }
        wsum[tid] = y;
    }
    __syncthreads();
    int woff = (wv > 0) ? wsum[wv - 1] : 0;
    if (i < n) rowptr[i] = woff + x - v;   // block-local exclusive
    if (tid == 0) bsum[blockIdx.x] = wsum[15];
}

__global__ void scan_tops(int* __restrict__ bsum, int* __restrict__ rowptr, int nb, int n) {
    const int tid = threadIdx.x;           // blockDim.x == 64
    int v = (tid < nb) ? bsum[tid] : 0;
    int x = v;
#pragma unroll
    for (int off = 1; off < 64; off <<= 1) {
        int t = __shfl_up(x, off);
        if (tid >= off) x += t;
    }
    if (tid < nb) bsum[tid] = x - v;       // exclusive block offsets
    if (tid == 63) rowptr[n] = x;          // grand total
}

__global__ void scan_add(int* __restrict__ rowptr, const int* __restrict__ bsum, int n) {
    int b = blockIdx.x;
    int i = b * 1024 + threadIdx.x;
    if (i < n && b > 0) rowptr[i] += bsum[b];
}

__global__ void scatter_kernel(const int* __restrict__ src, const int* __restrict__ dst,
                               const int* __restrict__ rowptr, int* __restrict__ cursor,
                               int* __restrict__ srcs, int* __restrict__ dsts, int E) {
    int i = blockIdx.x * blockDim.x + threadIdx.x;
    if (i < E) {
        int d = dst[i];
        int p = rowptr[d] + atomicAdd(&cursor[d], 1);
        srcs[p] = src[i];
        dsts[p] = d;
    }
}

// ---------------- W pre-pack into MFMA B-fragment order ----------------
// B-frag (16x16x32): lane l, elem e -> B[k = ks*32 + (l>>4)*8 + e][col = ct*16 + (l&15)]
// Wp[((ct*KS + ks)*64 + l)*8 + e]
template <int K, int FOUT>
__global__ void pack_w(const float* __restrict__ W, _Float16* __restrict__ Wp) {
    constexpr int KS = K / 32;
    constexpr int CT = FOUT / 16;
    int idx = blockIdx.x * blockDim.x + threadIdx.x;
    if (idx >= CT * KS * 64) return;
    int l = idx & 63;
    int ks = (idx >> 6) % KS;
    int ct = idx / (64 * KS);
    int kbase = ks * 32 + (l >> 4) * 8;
    int col = ct * 16 + (l & 15);
    h8v v;
#pragma unroll
    for (int e = 0; e < 8; e++) v[e] = (_Float16)W[(size_t)(kbase + e) * FOUT + col];
    *reinterpret_cast<h8v*>(&Wp[(size_t)idx * 8]) = v;
}

// ---------------- layer-1 fused GEMM + el/er (tiny FIN=6, vector ALU) -------
template <int FIN, int FOUT, int D, bool RELU_IN>
__global__ void gemm_att(const float* __restrict__ A, const float* __restrict__ bin,
                         const float* __restrict__ W, const float* __restrict__ al,
                         const float* __restrict__ ar, _Float16* __restrict__ feat,
                         float* __restrict__ el, float* __restrict__ er, int N) {
    constexpr int R = 16;
    constexpr int H = FOUT / D;
    constexpr int T = FOUT / 2;
    __shared__ __align__(16) float As[FIN][R + 4];
    const int j = threadIdx.x;            // 0..T-1
    const int h0 = j / D;
    const int h1 = (j + T) / D;
    const float alv0 = al[j],     arv0 = ar[j];
    const float alv1 = al[j + T], arv1 = ar[j + T];
    const int row0 = blockIdx.x * R;

    for (int idx = threadIdx.x; idx < R * FIN; idx += T) {
        int r = idx / FIN, k = idx % FIN;
        int rr = row0 + r;
        float v = 0.f;
        if (rr < N) {
            v = A[(size_t)rr * FIN + k];
            if constexpr (RELU_IN) { v += bin[k]; v = fmaxf(v, 0.f); }
        }
        As[k][r] = v;
    }
    __syncthreads();

    float acc0[R], acc1[R];
#pragma unroll
    for (int r = 0; r < R; r++) { acc0[r] = 0.f; acc1[r] = 0.f; }

    for (int k = 0; k < FIN; k++) {
        float w0 = W[(size_t)k * FOUT + j];
        float w1 = W[(size_t)k * FOUT + j + T];
        const float4* ap = reinterpret_cast<const float4*>(&As[k][0]);
        float av[16];
        *reinterpret_cast<float4*>(&av[0])  = ap[0];
        *reinterpret_cast<float4*>(&av[4])  = ap[1];
        *reinterpret_cast<float4*>(&av[8])  = ap[2];
        *reinterpret_cast<float4*>(&av[12]) = ap[3];
#pragma unroll
        for (int r = 0; r < R; r++) {
            acc0[r] += av[r] * w0;
            acc1[r] += av[r] * w1;
        }
    }

#pragma unroll
    for (int r = 0; r < R; r++) {
        int rr = row0 + r;
        if (rr >= N) break;
        float v0 = acc0[r], v1 = acc1[r];
        feat[(size_t)rr * FOUT + j] = (_Float16)v0;
        feat[(size_t)rr * FOUT + j + T] = (_Float16)v1;
        float vl0 = v0 * alv0, vr0 = v0 * arv0;
        float vl1 = v1 * alv1, vr1 = v1 * arv1;
#pragma unroll
        for (int off = D / 2; off >= 1; off >>= 1) {
            vl0 += __shfl_xor(vl0, off);
            vr0 += __shfl_xor(vr0, off);
            vl1 += __shfl_xor(vl1, off);
            vr1 += __shfl_xor(vr1, off);
        }
        if ((j % D) == 0) {
            el[(size_t)rr * H + h0] = vl0;
            er[(size_t)rr * H + h0] = vr0;
            el[(size_t)rr * H + h1] = vl1;
            er[(size_t)rr * H + h1] = vr1;
        }
    }
}

// ---------------- layers 2/3: MFMA fp16 GEMM + fused el/er ----------------
// 256 threads = 4 waves. Block covers RB=32 rows x FOUT cols.
// Wave w: row-tile rt = w>>1 (16 rows), col-half ch = w&1 (FOUT/2 cols).
// A staged in LDS fp16 (bias+relu fused), W pre-packed in B-frag order (L2).
template <int K, int FOUT, int D, bool RELU_IN>
__global__ __launch_bounds__(256)
void gemm_mfma(const float* __restrict__ A, const float* __restrict__ bin,
               const _Float16* __restrict__ Wp, const float* __restrict__ al,
               const float* __restrict__ ar, _Float16* __restrict__ feat,
               float* __restrict__ el, float* __restrict__ er, int N) {
    constexpr int RB  = 32;
    constexpr int KS  = K / 32;           // 4 k-steps
    constexpr int CHW = FOUT / 2;         // cols per wave
    constexpr int CTW = CHW / 16;         // col-tiles per wave (8 or 4)
    constexpr int CTH = D / 16;           // col-tiles per head (4 or 2)
    constexpr int HW  = CTW / CTH;        // heads per wave (2)
    constexpr int H   = FOUT / D;
    constexpr int STR = K + 8;            // LDS row stride (fp16), 16B-aligned
    __shared__ _Float16 As[RB * STR];
    const int tid = threadIdx.x;
    const int w  = tid >> 6;
    const int l  = tid & 63;
    const int rt = w >> 1;
    const int ch = w & 1;
    const int row0 = blockIdx.x * RB;

    // ---- stage A tile: fp32 -> (bias+relu) -> fp16 LDS ----
    constexpr int NV4 = RB * K / 4;
    for (int v = tid; v < NV4; v += 256) {
        int r  = v / (K / 4);
        int kv = (v % (K / 4)) * 4;
        int rr = row0 + r;
        float4 x = {0.f, 0.f, 0.f, 0.f};
        if (rr < N) {
            x = *reinterpret_cast<const float4*>(&A[(size_t)rr * K + kv]);
            if constexpr (RELU_IN) {
                float4 bv = *reinterpret_cast<const float4*>(&bin[kv]);
                x.x = fmaxf(x.x + bv.x, 0.f);
                x.y = fmaxf(x.y + bv.y, 0.f);
                x.z = fmaxf(x.z + bv.z, 0.f);
                x.w = fmaxf(x.w + bv.w, 0.f);
            }
        }
        h4 hv;
        hv[0] = (_Float16)x.x; hv[1] = (_Float16)x.y;
        hv[2] = (_Float16)x.z; hv[3] = (_Float16)x.w;
        *reinterpret_cast<h4*>(&As[r * STR + kv]) = hv;
    }
    __syncthreads();

    // ---- A fragments (row = rt*16 + (l&15), k = ks*32 + (l>>4)*8 + e) ----
    h8v afrag[KS];
    {
        const _Float16* base = &As[(rt * 16 + (l & 15)) * STR + ((l >> 4) * 8)];
#pragma unroll
        for (int ks = 0; ks < KS; ks++)
            afrag[ks] = *reinterpret_cast<const h8v*>(&base[ks * 32]);
    }

    // ---- B streaming + MFMA, double-buffered over col-tiles ----
    const h8v* Wv = reinterpret_cast<const h8v*>(Wp);
    const int ct0 = ch * CTW;
    f4v acc[CTW];
#pragma unroll
    for (int c = 0; c < CTW; c++) acc[c] = (f4v){0.f, 0.f, 0.f, 0.f};

    h8v bfr[2][KS];
#pragma unroll
    for (int ks = 0; ks < KS; ks++) bfr[0][ks] = Wv[(size_t)((ct0 * KS + ks) * 64 + l)];
#pragma unroll
    for (int c = 0; c < CTW; c++) {
        const int cur = c & 1, nxt = cur ^ 1;
        if (c + 1 < CTW) {
#pragma unroll
            for (int ks = 0; ks < KS; ks++)
                bfr[nxt][ks] = Wv[(size_t)(((ct0 + c + 1) * KS + ks) * 64 + l)];
        }
#pragma unroll
        for (int ks = 0; ks < KS; ks++)
            acc[c] = __builtin_amdgcn_mfma_f32_16x16x32_f16(afrag[ks], bfr[cur][ks], acc[c], 0, 0, 0);
    }

    // ---- epilogue: feat fp16 store + el/er (D row = (l>>4)*4+reg, col = l&15) ----
    float elp[HW][4], erp[HW][4];
#pragma unroll
    for (int hh = 0; hh < HW; hh++)
#pragma unroll
        for (int r = 0; r < 4; r++) { elp[hh][r] = 0.f; erp[hh][r] = 0.f; }

#pragma unroll
    for (int c = 0; c < CTW; c++) {
        const int col = ch * CHW + c * 16 + (l & 15);
        const float alv = al[col], arv = ar[col];
        const int hh = c / CTH;
#pragma unroll
        for (int r = 0; r < 4; r++) {
            float v = acc[c][r];
            elp[hh][r] += v * alv;
            erp[hh][r] += v * arv;
            int rr = row0 + rt * 16 + (l >> 4) * 4 + r;
            if (rr < N) feat[(size_t)rr * FOUT + col] = (_Float16)v;
        }
    }
#pragma unroll
    for (int hh = 0; hh < HW; hh++) {
#pragma unroll
        for (int r = 0; r < 4; r++) {
            float v = elp[hh][r], u = erp[hh][r];
#pragma unroll
            for (int off = 8; off >= 1; off >>= 1) {
                v += __shfl_xor(v, off);
                u += __shfl_xor(u, off);
            }
            if ((l & 15) == 0) {
                int rr = row0 + rt * 16 + (l >> 4) * 4 + r;
                if (rr < N) {
                    int hg = ch * HW + hh;
                    el[(size_t)rr * H + hg] = v;
                    er[(size_t)rr * H + hg] = u;
                }
            }
        }
    }
}

// ---------------- edge-parallel attention logits ----------------
__global__ void edge_x_kernel(const int* __restrict__ srcs, const int* __restrict__ dsts,
                              const float4* __restrict__ el, const float4* __restrict__ er,
                              float4* __restrict__ xbuf, int E) {
    int i = blockIdx.x * blockDim.x + threadIdx.x;
    if (i >= E) return;
    int u = srcs[i], d = dsts[i];
    float4 l = el[u], r = er[d];
    float4 x;
    x.x = l.x + r.x; x.x = x.x > 0.f ? x.x : 0.2f * x.x;
    x.y = l.y + r.y; x.y = x.y > 0.f ? x.y : 0.2f * x.y;
    x.z = l.z + r.z; x.z = x.z > 0.f ? x.z : 0.2f * x.z;
    x.w = l.w + r.w; x.w = x.w > 0.f ? x.w : 0.2f * x.w;
    xbuf[i] = x;
}

// ---------------- per-dst-node edge softmax + aggregation ----------------
template <int H, int D>
__global__ void agg_kernel(const h4* __restrict__ featH, const float4* __restrict__ xbuf4,
                           const int* __restrict__ srcs, const int* __restrict__ rowptr,
                           float4* __restrict__ out4, int N) {
    constexpr int HD = H * D;
    constexpr int TPN = HD / 4;          // 32 or 64
    constexpr int NPB = 256 / TPN;       // 8 or 4
    const int tid = threadIdx.x;
    const int ln = tid % TPN;
    const int node = blockIdx.x * NPB + tid / TPN;
    if (node >= N) return;
    const int h = (ln * 4) / D;
    const int beg = rowptr[node], end = rowptr[node + 1];

    float mx = -3.4e38f, my = -3.4e38f, mz = -3.4e38f, mw = -3.4e38f;
    float sx = 0.f, sy = 0.f, sz = 0.f, sw = 0.f;
    for (int i = beg + ln; i < end; i += TPN) {
        float4 x = xbuf4[i];
        float t;
        t = fmaxf(mx, x.x); sx = sx * __expf(mx - t) + __expf(x.x - t); mx = t;
        t = fmaxf(my, x.y); sy = sy * __expf(my - t) + __expf(x.y - t); my = t;
        t = fmaxf(mz, x.z); sz = sz * __expf(mz - t) + __expf(x.z - t); mz = t;
        t = fmaxf(mw, x.w); sw = sw * __expf(mw - t) + __expf(x.w - t); mw = t;
    }
#pragma unroll
    for (int off = TPN / 2; off >= 1; off >>= 1) {
        float m2, s2, t;
        m2 = __shfl_xor(mx, off); s2 = __shfl_xor(sx, off);
        t = fmaxf(mx, m2); sx = sx * __expf(mx - t) + s2 * __expf(m2 - t); mx = t;
        m2 = __shfl_xor(my, off); s2 = __shfl_xor(sy, off);
        t = fmaxf(my, m2); sy = sy * __expf(my - t) + s2 * __expf(m2 - t); my = t;
        m2 = __shfl_xor(mz, off); s2 = __shfl_xor(sz, off);
        t = fmaxf(mz, m2); sz = sz * __expf(mz - t) + s2 * __expf(m2 - t); mz = t;
        m2 = __shfl_xor(mw, off); s2 = __shfl_xor(sw, off);
        t = fmaxf(mw, m2); sw = sw * __expf(mw - t) + s2 * __expf(m2 - t); mw = t;
    }
    const float m = (h == 0) ? mx : (h == 1) ? my : (h == 2) ? mz : mw;
    const float s = (h == 0) ? sx : (h == 1) ? sy : (h == 2) ? sz : sw;
    const float inv = (s > 0.f) ? 1.f / s : 0.f;

    const float* xb = (const float*)xbuf4;
    float4 a0 = {0,0,0,0}, a1 = {0,0,0,0}, a2 = {0,0,0,0}, a3 = {0,0,0,0};
    int i = beg;
    for (; i + 4 <= end; i += 4) {
        int u0 = srcs[i], u1 = srcs[i + 1], u2 = srcs[i + 2], u3 = srcs[i + 3];
        float x0 = xb[(size_t)i * 4 + h];
        float x1 = xb[(size_t)(i + 1) * 4 + h];
        float x2 = xb[(size_t)(i + 2) * 4 + h];
        float x3 = xb[(size_t)(i + 3) * 4 + h];
        h4 f0 = featH[(size_t)u0 * TPN + ln];
        h4 f1 = featH[(size_t)u1 * TPN + ln];
        h4 f2 = featH[(size_t)u2 * TPN + ln];
        h4 f3 = featH[(size_t)u3 * TPN + ln];
        float w0 = __expf(x0 - m), w1 = __expf(x1 - m);
        float w2 = __expf(x2 - m), w3 = __expf(x3 - m);
        a0.x += w0 * (float)f0[0]; a0.y += w0 * (float)f0[1];
        a0.z += w0 * (float)f0[2]; a0.w += w0 * (float)f0[3];
        a1.x += w1 * (float)f1[0]; a1.y += w1 * (float)f1[1];
        a1.z += w1 * (float)f1[2]; a1.w += w1 * (float)f1[3];
        a2.x += w2 * (float)f2[0]; a2.y += w2 * (float)f2[1];
        a2.z += w2 * (float)f2[2]; a2.w += w2 * (float)f2[3];
        a3.x += w3 * (float)f3[0]; a3.y += w3 * (float)f3[1];
        a3.z += w3 * (float)f3[2]; a3.w += w3 * (float)f3[3];
    }
    for (; i < end; i++) {
        int u = srcs[i];
        float x = xb[(size_t)i * 4 + h];
        h4 f = featH[(size_t)u * TPN + ln];
        float wq = __expf(x - m);
        a0.x += wq * (float)f[0]; a0.y += wq * (float)f[1];
        a0.z += wq * (float)f[2]; a0.w += wq * (float)f[3];
    }
    float4 o;
    o.x = ((a0.x + a1.x) + (a2.x + a3.x)) * inv;
    o.y = ((a0.y + a1.y) + (a2.y + a3.y)) * inv;
    o.z = ((a0.z + a1.z) + (a2.z + a3.z)) * inv;
    o.w = ((a0.w + a1.w) + (a2.w + a3.w)) * inv;
    out4[(size_t)node * TPN + ln] = o;
}

// ---------------- batched-graph mean readout ----------------

__device__ __forceinline__ int lower_bound_i(const int* __restrict__ a, int n, int key) {
    int lo = 0, hi = n;
    while (lo < hi) {
        int mid = (lo + hi) >> 1;
        if (a[mid] < key) lo = mid + 1; else hi = mid;
    }
    return lo;
}

__global__ void readout_partial(const float* __restrict__ agg, const int* __restrict__ gid,
                                float* __restrict__ part, int N, int C, int SL) {
    int g = blockIdx.x / SL, slice = blockIdx.x % SL;
    int c = threadIdx.x;
    int start = lower_bound_i(gid, N, g);
    int end = lower_bound_i(gid, N, g + 1);
    float sum = 0.f;
    for (int n = start + slice; n < end; n += SL) sum += agg[(size_t)n * C + c];
    part[((size_t)g * SL + slice) * C + c] = sum;
}

__global__ void readout_final(const float* __restrict__ part, const float* __restrict__ b3,
                              const int* __restrict__ gid, float* __restrict__ out,
                              int N, int C, int SL) {
    int g = blockIdx.x, c = threadIdx.x;
    int start = lower_bound_i(gid, N, g);
    int end = lower_bound_i(gid, N, g + 1);
    int cnt = end - start;
    float s = 0.f;
    for (int k = 0; k < SL; k++) s += part[((size_t)g * SL + k) * C + c];
    out[(size_t)g * C + c] = (cnt > 0) ? s / (float)cnt + b3[c] : 0.f;
}

// ---------------- launch ----------------

extern "C" void kernel_launch(void* const* d_in, const int* in_sizes, int n_in,
                              void* d_out, int out_size, void* d_ws, size_t ws_size,
                              hipStream_t stream) {
    const float* feat0 = (const float*)d_in[0];
    const int* src = (const int*)d_in[1];
    const int* dst = (const int*)d_in[2];
    const int* gid = (const int*)d_in[3];
    const float* W1 = (const float*)d_in[4];
    const float* al1 = (const float*)d_in[5];
    const float* ar1 = (const float*)d_in[6];
    const float* b1 = (const float*)d_in[7];
    const float* W2 = (const float*)d_in[8];
    const float* al2 = (const float*)d_in[9];
    const float* ar2 = (const float*)d_in[10];
    const float* b2 = (const float*)d_in[11];
    const float* W3 = (const float*)d_in[12];
    const float* al3 = (const float*)d_in[13];
    const float* ar3 = (const float*)d_in[14];
    const float* b3 = (const float*)d_in[15];

    const int N = in_sizes[0] / 6;       // 30000
    const int E = in_sizes[1];           // 480000
    const int G = 64;
    const int SL = 8;
    float* out = (float*)d_out;

    char* wsp = (char*)d_ws;
    auto alloc = [&](size_t bytes) -> char* {
        char* p = wsp;
        wsp += (bytes + 255) & ~(size_t)255;
        return p;
    };
    int* counts   = (int*)alloc((size_t)N * 4);
    int* rowptr   = (int*)alloc((size_t)(N + 1) * 4);
    int* cursor   = (int*)alloc((size_t)N * 4);
    int* bsum     = (int*)alloc(64 * 4);
    int* srcs     = (int*)alloc((size_t)E * 4);
    int* dsts     = (int*)alloc((size_t)E * 4);
    float* xbuf   = (float*)alloc((size_t)E * 4 * 4);
    float* el     = (float*)alloc((size_t)N * 4 * 4);
    float* er     = (float*)alloc((size_t)N * 4 * 4);
    _Float16* featH = (_Float16*)alloc((size_t)N * 256 * 2);
    float* aggB   = (float*)alloc((size_t)N * 256 * 4);
    float* part   = (float*)alloc((size_t)G * SL * 256 * 4);
    _Float16* Wp2 = (_Float16*)alloc((size_t)128 * 128 * 2);
    _Float16* Wp3 = (_Float16*)alloc((size_t)128 * 256 * 2);

    // CSR build
    const int nb = (N + 1023) / 1024;
    const int zspan = (int)(((char*)bsum - (char*)counts) / 4) + 64;
    zero_i32<<<dim3((zspan + 255) / 256), dim3(256), 0, stream>>>(counts, zspan);
    hist_kernel<<<dim3((E + 255) / 256), dim3(256), 0, stream>>>(dst, counts, E);
    scan_block<<<dim3(nb), dim3(1024), 0, stream>>>(counts, rowptr, bsum, N);
    scan_tops<<<dim3(1), dim3(64), 0, stream>>>(bsum, rowptr, nb, N);
    scan_add<<<dim3(nb), dim3(1024), 0, stream>>>(rowptr, bsum, N);
    scatter_kernel<<<dim3((E + 255) / 256), dim3(256), 0, stream>>>(
        src, dst, rowptr, cursor, srcs, dsts, E);

    // W pre-pack (fp16, MFMA B-frag order)
    pack_w<128, 128><<<dim3(8), dim3(256), 0, stream>>>(W2, Wp2);
    pack_w<128, 256><<<dim3(16), dim3(256), 0, stream>>>(W3, Wp3);

    const int edgeGrid = (E + 255) / 256;

    // layer 1 (vector GEMM, K=6)
    gemm_att<6, 128, 32, false><<<dim3((N + 15) / 16), dim3(64), 0, stream>>>(
        feat0, nullptr, W1, al1, ar1, featH, el, er, N);
    edge_x_kernel<<<dim3(edgeGrid), dim3(256), 0, stream>>>(
        srcs, dsts, (const float4*)el, (const float4*)er, (float4*)xbuf, E);
    agg_kernel<4, 32><<<dim3((N + 7) / 8), dim3(256), 0, stream>>>(
        (const h4*)featH, (const float4*)xbuf, srcs, rowptr, (float4*)aggB, N);

    // layer 2 (MFMA; relu(prev + b1) fused into A staging)
    gemm_mfma<128, 128, 32, true><<<dim3((N + 31) / 32), dim3(256), 0, stream>>>(
        aggB, b1, Wp2, al2, ar2, featH, el, er, N);
    edge_x_kernel<<<dim3(edgeGrid), dim3(256), 0, stream>>>(
        srcs, dsts, (const float4*)el, (const float4*)er, (float4*)xbuf, E);
    agg_kernel<4, 32><<<dim3((N + 7) / 8), dim3(256), 0, stream>>>(
        (const h4*)featH, (const float4*)xbuf, srcs, rowptr, (float4*)aggB, N);

    // layer 3 (MFMA)
    gemm_mfma<128, 256, 64, true><<<dim3((N + 31) / 32), dim3(256), 0, stream>>>(
        aggB, b2, Wp3, al3, ar3, featH, el, er, N);
    edge_x_kernel<<<dim3(edgeGrid), dim3(256), 0, stream>>>(
        srcs, dsts, (const float4*)el, (const float4*)er, (float4*)xbuf, E);
    agg_kernel<4, 64><<<dim3((N + 3) / 4), dim3(256), 0, stream>>>(
        (const h4*)featH, (const float4*)xbuf, srcs, rowptr, (float4*)aggB, N);

    // readout
    readout_partial<<<dim3(G * SL), dim3(256), 0, stream>>>(aggB, gid, part, N, 256, SL);
    readout_final<<<dim3(G), dim3(256), 0, stream>>>(part, b3, gid, out, N, 256, SL);
}

// Round 7
// 213.455 us; speedup vs baseline: 3.8686x; 1.2318x over previous
//
#include <hip/hip_runtime.h>

typedef _Float16 h4 __attribute__((ext_vector_type(4)));
typedef _Float16 h8v __attribute__((ext_vector_type(8)));
typedef float f4v __attribute__((ext_vector_type(4)));
typedef float f32x8 __attribute__((ext_vector_type(8)));

// ---------------- CSR construction ----------------

__global__ void zero_i32(int* __restrict__ p, int n) {
    int i = blockIdx.x * blockDim.x + threadIdx.x;
    if (i < n) p[i] = 0;
}

__global__ void hist_kernel(const int* __restrict__ dst, int* __restrict__ counts, int E) {
    int i = blockIdx.x * blockDim.x + threadIdx.x;
    if (i < E) atomicAdd(&counts[dst[i]], 1);
}

__global__ void scan_block(const int* __restrict__ counts, int* __restrict__ rowptr,
                           int* __restrict__ bsum, int n) {
    __shared__ int wsum[16];
    const int tid = threadIdx.x;           // blockDim.x == 1024
    const int lane = tid & 63, wv = tid >> 6;
    const int i = blockIdx.x * 1024 + tid;
    int v = (i < n) ? counts[i] : 0;
    int x = v;
#pragma unroll
    for (int off = 1; off < 64; off <<= 1) {
        int t = __shfl_up(x, off);
        if (lane >= off) x += t;
    }
    if (lane == 63) wsum[wv] = x;
    __syncthreads();
    if (tid < 16) {
        int y = wsum[tid];
#pragma unroll
        for (int off = 1; off < 16; off <<= 1) {
            int t = __shfl_up(y, off);
            if (tid >= off) y += t;
        }
        wsum[tid] = y;
    }
    __syncthreads();
    int woff = (wv > 0) ? wsum[wv - 1] : 0;
    if (i < n) rowptr[i] = woff + x - v;   // block-local exclusive
    if (tid == 0) bsum[blockIdx.x] = wsum[15];
}

__global__ void scan_tops(int* __restrict__ bsum, int* __restrict__ rowptr, int nb, int n) {
    const int tid = threadIdx.x;           // blockDim.x == 64
    int v = (tid < nb) ? bsum[tid] : 0;
    int x = v;
#pragma unroll
    for (int off = 1; off < 64; off <<= 1) {
        int t = __shfl_up(x, off);
        if (tid >= off) x += t;
    }
    if (tid < nb) bsum[tid] = x - v;       // exclusive block offsets
    if (tid == 63) rowptr[n] = x;          // grand total
}

__global__ void scan_add(int* __restrict__ rowptr, const int* __restrict__ bsum, int n) {
    int b = blockIdx.x;
    int i = b * 1024 + threadIdx.x;
    if (i < n && b > 0) rowptr[i] += bsum[b];
}

__global__ void scatter_kernel(const int* __restrict__ src, const int* __restrict__ dst,
                               const int* __restrict__ rowptr, int* __restrict__ cursor,
                               int* __restrict__ srcs, int E) {
    int i = blockIdx.x * blockDim.x + threadIdx.x;
    if (i < E) {
        int d = dst[i];
        int p = rowptr[d] + atomicAdd(&cursor[d], 1);
        srcs[p] = src[i];
    }
}

// ---------------- W pre-pack into MFMA B-fragment order ----------------
// B-frag (16x16x32): lane l, elem e -> B[k = ks*32 + (l>>4)*8 + e][col = ct*16 + (l&15)]
template <int K, int FOUT>
__global__ void pack_w(const float* __restrict__ W, _Float16* __restrict__ Wp) {
    constexpr int KS = K / 32;
    constexpr int CT = FOUT / 16;
    int idx = blockIdx.x * blockDim.x + threadIdx.x;
    if (idx >= CT * KS * 64) return;
    int l = idx & 63;
    int ks = (idx >> 6) % KS;
    int ct = idx / (64 * KS);
    int kbase = ks * 32 + (l >> 4) * 8;
    int col = ct * 16 + (l & 15);
    h8v v;
#pragma unroll
    for (int e = 0; e < 8; e++) v[e] = (_Float16)W[(size_t)(kbase + e) * FOUT + col];
    *reinterpret_cast<h8v*>(&Wp[(size_t)idx * 8]) = v;
}

// ---------------- layer-1 fused GEMM + el/er (tiny FIN=6, vector ALU) -------
template <int FIN, int FOUT, int D, bool RELU_IN>
__global__ void gemm_att(const float* __restrict__ A, const float* __restrict__ bin,
                         const float* __restrict__ W, const float* __restrict__ al,
                         const float* __restrict__ ar, _Float16* __restrict__ feat,
                         float* __restrict__ el, float* __restrict__ er, int N) {
    constexpr int R = 16;
    constexpr int H = FOUT / D;
    constexpr int T = FOUT / 2;
    __shared__ __align__(16) float As[FIN][R + 4];
    const int j = threadIdx.x;            // 0..T-1
    const int h0 = j / D;
    const int h1 = (j + T) / D;
    const float alv0 = al[j],     arv0 = ar[j];
    const float alv1 = al[j + T], arv1 = ar[j + T];
    const int row0 = blockIdx.x * R;

    for (int idx = threadIdx.x; idx < R * FIN; idx += T) {
        int r = idx / FIN, k = idx % FIN;
        int rr = row0 + r;
        float v = 0.f;
        if (rr < N) {
            v = A[(size_t)rr * FIN + k];
            if constexpr (RELU_IN) { v += bin[k]; v = fmaxf(v, 0.f); }
        }
        As[k][r] = v;
    }
    __syncthreads();

    float acc0[R], acc1[R];
#pragma unroll
    for (int r = 0; r < R; r++) { acc0[r] = 0.f; acc1[r] = 0.f; }

    for (int k = 0; k < FIN; k++) {
        float w0 = W[(size_t)k * FOUT + j];
        float w1 = W[(size_t)k * FOUT + j + T];
        const float4* ap = reinterpret_cast<const float4*>(&As[k][0]);
        float av[16];
        *reinterpret_cast<float4*>(&av[0])  = ap[0];
        *reinterpret_cast<float4*>(&av[4])  = ap[1];
        *reinterpret_cast<float4*>(&av[8])  = ap[2];
        *reinterpret_cast<float4*>(&av[12]) = ap[3];
#pragma unroll
        for (int r = 0; r < R; r++) {
            acc0[r] += av[r] * w0;
            acc1[r] += av[r] * w1;
        }
    }

#pragma unroll
    for (int r = 0; r < R; r++) {
        int rr = row0 + r;
        if (rr >= N) break;
        float v0 = acc0[r], v1 = acc1[r];
        feat[(size_t)rr * FOUT + j] = (_Float16)v0;
        feat[(size_t)rr * FOUT + j + T] = (_Float16)v1;
        float vl0 = v0 * alv0, vr0 = v0 * arv0;
        float vl1 = v1 * alv1, vr1 = v1 * arv1;
#pragma unroll
        for (int off = D / 2; off >= 1; off >>= 1) {
            vl0 += __shfl_xor(vl0, off);
            vr0 += __shfl_xor(vr0, off);
            vl1 += __shfl_xor(vl1, off);
            vr1 += __shfl_xor(vr1, off);
        }
        if ((j % D) == 0) {
            el[(size_t)rr * H + h0] = vl0;
            er[(size_t)rr * H + h0] = vr0;
            el[(size_t)rr * H + h1] = vl1;
            er[(size_t)rr * H + h1] = vr1;
        }
    }
}

// ---------------- layers 2/3: MFMA fp16 GEMM + fused el/er ----------------
template <int K, int FOUT, int D, bool RELU_IN>
__global__ __launch_bounds__(256)
void gemm_mfma(const float* __restrict__ A, const float* __restrict__ bin,
               const _Float16* __restrict__ Wp, const float* __restrict__ al,
               const float* __restrict__ ar, _Float16* __restrict__ feat,
               float* __restrict__ el, float* __restrict__ er, int N) {
    constexpr int RB  = 32;
    constexpr int KS  = K / 32;           // 4 k-steps
    constexpr int CHW = FOUT / 2;         // cols per wave
    constexpr int CTW = CHW / 16;         // col-tiles per wave
    constexpr int CTH = D / 16;           // col-tiles per head
    constexpr int HW  = CTW / CTH;        // heads per wave (2)
    constexpr int H   = FOUT / D;
    constexpr int STR = K + 8;            // LDS row stride (fp16)
    __shared__ _Float16 As[RB * STR];
    const int tid = threadIdx.x;
    const int w  = tid >> 6;
    const int l  = tid & 63;
    const int rt = w >> 1;
    const int ch = w & 1;
    const int row0 = blockIdx.x * RB;

    constexpr int NV4 = RB * K / 4;
    for (int v = tid; v < NV4; v += 256) {
        int r  = v / (K / 4);
        int kv = (v % (K / 4)) * 4;
        int rr = row0 + r;
        float4 x = {0.f, 0.f, 0.f, 0.f};
        if (rr < N) {
            x = *reinterpret_cast<const float4*>(&A[(size_t)rr * K + kv]);
            if constexpr (RELU_IN) {
                float4 bv = *reinterpret_cast<const float4*>(&bin[kv]);
                x.x = fmaxf(x.x + bv.x, 0.f);
                x.y = fmaxf(x.y + bv.y, 0.f);
                x.z = fmaxf(x.z + bv.z, 0.f);
                x.w = fmaxf(x.w + bv.w, 0.f);
            }
        }
        h4 hv;
        hv[0] = (_Float16)x.x; hv[1] = (_Float16)x.y;
        hv[2] = (_Float16)x.z; hv[3] = (_Float16)x.w;
        *reinterpret_cast<h4*>(&As[r * STR + kv]) = hv;
    }
    __syncthreads();

    h8v afrag[KS];
    {
        const _Float16* base = &As[(rt * 16 + (l & 15)) * STR + ((l >> 4) * 8)];
#pragma unroll
        for (int ks = 0; ks < KS; ks++)
            afrag[ks] = *reinterpret_cast<const h8v*>(&base[ks * 32]);
    }

    const h8v* Wv = reinterpret_cast<const h8v*>(Wp);
    const int ct0 = ch * CTW;
    f4v acc[CTW];
#pragma unroll
    for (int c = 0; c < CTW; c++) acc[c] = (f4v){0.f, 0.f, 0.f, 0.f};

    h8v bfr[2][KS];
#pragma unroll
    for (int ks = 0; ks < KS; ks++) bfr[0][ks] = Wv[(size_t)((ct0 * KS + ks) * 64 + l)];
#pragma unroll
    for (int c = 0; c < CTW; c++) {
        const int cur = c & 1, nxt = cur ^ 1;
        if (c + 1 < CTW) {
#pragma unroll
            for (int ks = 0; ks < KS; ks++)
                bfr[nxt][ks] = Wv[(size_t)(((ct0 + c + 1) * KS + ks) * 64 + l)];
        }
#pragma unroll
        for (int ks = 0; ks < KS; ks++)
            acc[c] = __builtin_amdgcn_mfma_f32_16x16x32_f16(afrag[ks], bfr[cur][ks], acc[c], 0, 0, 0);
    }

    float elp[HW][4], erp[HW][4];
#pragma unroll
    for (int hh = 0; hh < HW; hh++)
#pragma unroll
        for (int r = 0; r < 4; r++) { elp[hh][r] = 0.f; erp[hh][r] = 0.f; }

#pragma unroll
    for (int c = 0; c < CTW; c++) {
        const int col = ch * CHW + c * 16 + (l & 15);
        const float alv = al[col], arv = ar[col];
        const int hh = c / CTH;
#pragma unroll
        for (int r = 0; r < 4; r++) {
            float v = acc[c][r];
            elp[hh][r] += v * alv;
            erp[hh][r] += v * arv;
            int rr = row0 + rt * 16 + (l >> 4) * 4 + r;
            if (rr < N) feat[(size_t)rr * FOUT + col] = (_Float16)v;
        }
    }
#pragma unroll
    for (int hh = 0; hh < HW; hh++) {
#pragma unroll
        for (int r = 0; r < 4; r++) {
            float v = elp[hh][r], u = erp[hh][r];
#pragma unroll
            for (int off = 8; off >= 1; off >>= 1) {
                v += __shfl_xor(v, off);
                u += __shfl_xor(u, off);
            }
            if ((l & 15) == 0) {
                int rr = row0 + rt * 16 + (l >> 4) * 4 + r;
                if (rr < N) {
                    int hg = ch * HW + hh;
                    el[(size_t)rr * H + hg] = v;
                    er[(size_t)rr * H + hg] = u;
                }
            }
        }
    }
}

// ---------------- fused single-pass edge softmax + aggregation ----------------
// No max-subtraction (mathematically identical; logits O(+-10), exp safe in fp32).
// Each lane owns 8 contiguous channels (h8v 16B gathers); s accumulated
// redundantly per lane -> zero cross-lane ops. x computed inline from el/er.
template <int HD, int D>
__global__ __launch_bounds__(256)
void agg_fused(const h8v* __restrict__ featH8, const float* __restrict__ el,
               const float* __restrict__ er, const int* __restrict__ srcs,
               const int* __restrict__ rowptr, f32x8* __restrict__ out, int N) {
    constexpr int TPN = HD / 8;          // 16 (HD=128) or 32 (HD=256)
    constexpr int NPB = 256 / TPN;       // 16 or 8
    const int tid = threadIdx.x;
    const int ln = tid % TPN;
    const int node = blockIdx.x * NPB + tid / TPN;
    if (node >= N) return;
    const int h = ln / (D / 8);          // head of this lane's 8 channels
    const int beg = rowptr[node], end = rowptr[node + 1];
    const float ern = er[(size_t)node * 4 + h];

    float s = 0.f;
    f32x8 a0 = {0,0,0,0,0,0,0,0}, a1 = a0;
    int i = beg;
    for (; i + 4 <= end; i += 4) {
        int u0 = srcs[i], u1 = srcs[i + 1], u2 = srcs[i + 2], u3 = srcs[i + 3];
        float x0 = el[(size_t)u0 * 4 + h] + ern; x0 = x0 > 0.f ? x0 : 0.2f * x0;
        float x1 = el[(size_t)u1 * 4 + h] + ern; x1 = x1 > 0.f ? x1 : 0.2f * x1;
        float x2 = el[(size_t)u2 * 4 + h] + ern; x2 = x2 > 0.f ? x2 : 0.2f * x2;
        float x3 = el[(size_t)u3 * 4 + h] + ern; x3 = x3 > 0.f ? x3 : 0.2f * x3;
        h8v f0 = featH8[(size_t)u0 * TPN + ln];
        h8v f1 = featH8[(size_t)u1 * TPN + ln];
        h8v f2 = featH8[(size_t)u2 * TPN + ln];
        h8v f3 = featH8[(size_t)u3 * TPN + ln];
        float w0 = __expf(x0), w1 = __expf(x1);
        float w2 = __expf(x2), w3 = __expf(x3);
        s += (w0 + w1) + (w2 + w3);
#pragma unroll
        for (int k = 0; k < 8; k++) {
            a0[k] += w0 * (float)f0[k];
            a1[k] += w1 * (float)f1[k];
            a0[k] += w2 * (float)f2[k];
            a1[k] += w3 * (float)f3[k];
        }
    }
    for (; i < end; i++) {
        int u = srcs[i];
        float x = el[(size_t)u * 4 + h] + ern; x = x > 0.f ? x : 0.2f * x;
        h8v f = featH8[(size_t)u * TPN + ln];
        float w = __expf(x);
        s += w;
#pragma unroll
        for (int k = 0; k < 8; k++) a0[k] += w * (float)f[k];
    }
    const float inv = (s > 0.f) ? 1.f / s : 0.f;
    f32x8 o;
#pragma unroll
    for (int k = 0; k < 8; k++) o[k] = (a0[k] + a1[k]) * inv;
    out[(size_t)node * TPN + ln] = o;
}

// ---------------- batched-graph mean readout ----------------

__device__ __forceinline__ int lower_bound_i(const int* __restrict__ a, int n, int key) {
    int lo = 0, hi = n;
    while (lo < hi) {
        int mid = (lo + hi) >> 1;
        if (a[mid] < key) lo = mid + 1; else hi = mid;
    }
    return lo;
}

__global__ void readout_partial(const float* __restrict__ agg, const int* __restrict__ gid,
                                float* __restrict__ part, int N, int C, int SL) {
    int g = blockIdx.x / SL, slice = blockIdx.x % SL;
    int c = threadIdx.x;
    int start = lower_bound_i(gid, N, g);
    int end = lower_bound_i(gid, N, g + 1);
    float sum = 0.f;
    for (int n = start + slice; n < end; n += SL) sum += agg[(size_t)n * C + c];
    part[((size_t)g * SL + slice) * C + c] = sum;
}

__global__ void readout_final(const float* __restrict__ part, const float* __restrict__ b3,
                              const int* __restrict__ gid, float* __restrict__ out,
                              int N, int C, int SL) {
    int g = blockIdx.x, c = threadIdx.x;
    int start = lower_bound_i(gid, N, g);
    int end = lower_bound_i(gid, N, g + 1);
    int cnt = end - start;
    float s = 0.f;
    for (int k = 0; k < SL; k++) s += part[((size_t)g * SL + k) * C + c];
    out[(size_t)g * C + c] = (cnt > 0) ? s / (float)cnt + b3[c] : 0.f;
}

// ---------------- launch ----------------

extern "C" void kernel_launch(void* const* d_in, const int* in_sizes, int n_in,
                              void* d_out, int out_size, void* d_ws, size_t ws_size,
                              hipStream_t stream) {
    const float* feat0 = (const float*)d_in[0];
    const int* src = (const int*)d_in[1];
    const int* dst = (const int*)d_in[2];
    const int* gid = (const int*)d_in[3];
    const float* W1 = (const float*)d_in[4];
    const float* al1 = (const float*)d_in[5];
    const float* ar1 = (const float*)d_in[6];
    const float* b1 = (const float*)d_in[7];
    const float* W2 = (const float*)d_in[8];
    const float* al2 = (const float*)d_in[9];
    const float* ar2 = (const float*)d_in[10];
    const float* b2 = (const float*)d_in[11];
    const float* W3 = (const float*)d_in[12];
    const float* al3 = (const float*)d_in[13];
    const float* ar3 = (const float*)d_in[14];
    const float* b3 = (const float*)d_in[15];

    const int N = in_sizes[0] / 6;       // 30000
    const int E = in_sizes[1];           // 480000
    const int G = 64;
    const int SL = 8;
    float* out = (float*)d_out;

    char* wsp = (char*)d_ws;
    auto alloc = [&](size_t bytes) -> char* {
        char* p = wsp;
        wsp += (bytes + 255) & ~(size_t)255;
        return p;
    };
    int* counts   = (int*)alloc((size_t)N * 4);
    int* rowptr   = (int*)alloc((size_t)(N + 1) * 4);
    int* cursor   = (int*)alloc((size_t)N * 4);
    int* bsum     = (int*)alloc(64 * 4);
    int* srcs     = (int*)alloc((size_t)E * 4);
    float* el     = (float*)alloc((size_t)N * 4 * 4);
    float* er     = (float*)alloc((size_t)N * 4 * 4);
    _Float16* featH = (_Float16*)alloc((size_t)N * 256 * 2);
    float* aggB   = (float*)alloc((size_t)N * 256 * 4);
    float* part   = (float*)alloc((size_t)G * SL * 256 * 4);
    _Float16* Wp2 = (_Float16*)alloc((size_t)128 * 128 * 2);
    _Float16* Wp3 = (_Float16*)alloc((size_t)128 * 256 * 2);

    // CSR build
    const int nb = (N + 1023) / 1024;
    const int zspan = (int)(((char*)bsum - (char*)counts) / 4) + 64;
    zero_i32<<<dim3((zspan + 255) / 256), dim3(256), 0, stream>>>(counts, zspan);
    hist_kernel<<<dim3((E + 255) / 256), dim3(256), 0, stream>>>(dst, counts, E);
    scan_block<<<dim3(nb), dim3(1024), 0, stream>>>(counts, rowptr, bsum, N);
    scan_tops<<<dim3(1), dim3(64), 0, stream>>>(bsum, rowptr, nb, N);
    scan_add<<<dim3(nb), dim3(1024), 0, stream>>>(rowptr, bsum, N);
    scatter_kernel<<<dim3((E + 255) / 256), dim3(256), 0, stream>>>(
        src, dst, rowptr, cursor, srcs, E);

    // W pre-pack (fp16, MFMA B-frag order)
    pack_w<128, 128><<<dim3(8), dim3(256), 0, stream>>>(W2, Wp2);
    pack_w<128, 256><<<dim3(16), dim3(256), 0, stream>>>(W3, Wp3);

    // layer 1 (vector GEMM, K=6)
    gemm_att<6, 128, 32, false><<<dim3((N + 15) / 16), dim3(64), 0, stream>>>(
        feat0, nullptr, W1, al1, ar1, featH, el, er, N);
    agg_fused<128, 32><<<dim3((N + 15) / 16), dim3(256), 0, stream>>>(
        (const h8v*)featH, el, er, srcs, rowptr, (f32x8*)aggB, N);

    // layer 2 (MFMA; relu(prev + b1) fused into A staging)
    gemm_mfma<128, 128, 32, true><<<dim3((N + 31) / 32), dim3(256), 0, stream>>>(
        aggB, b1, Wp2, al2, ar2, featH, el, er, N);
    agg_fused<128, 32><<<dim3((N + 15) / 16), dim3(256), 0, stream>>>(
        (const h8v*)featH, el, er, srcs, rowptr, (f32x8*)aggB, N);

    // layer 3 (MFMA)
    gemm_mfma<128, 256, 64, true><<<dim3((N + 31) / 32), dim3(256), 0, stream>>>(
        aggB, b2, Wp3, al3, ar3, featH, el, er, N);
    agg_fused<256, 64><<<dim3((N + 7) / 8), dim3(256), 0, stream>>>(
        (const h8v*)featH, el, er, srcs, rowptr, (f32x8*)aggB, N);

    // readout
    readout_partial<<<dim3(G * SL), dim3(256), 0, stream>>>(aggB, gid, part, N, 256, SL);
    readout_final<<<dim3(G), dim3(256), 0, stream>>>(part, b3, gid, out, N, 256, SL);
}

// Round 8
// 209.912 us; speedup vs baseline: 3.9338x; 1.0169x over previous
//
#include <hip/hip_runtime.h>

typedef _Float16 h4 __attribute__((ext_vector_type(4)));
typedef _Float16 h8v __attribute__((ext_vector_type(8)));
typedef float f4v __attribute__((ext_vector_type(4)));
typedef float f32x8 __attribute__((ext_vector_type(8)));

// ---------------- CSR construction ----------------

__global__ void zero_i32(int* __restrict__ p, int n) {
    int i = blockIdx.x * blockDim.x + threadIdx.x;
    if (i < n) p[i] = 0;
}

__global__ void hist_kernel(const int* __restrict__ dst, int* __restrict__ counts, int E) {
    int i = blockIdx.x * blockDim.x + threadIdx.x;
    if (i < E) atomicAdd(&counts[dst[i]], 1);
}

__global__ void scan_block(const int* __restrict__ counts, int* __restrict__ rowptr,
                           int* __restrict__ bsum, int n) {
    __shared__ int wsum[16];
    const int tid = threadIdx.x;           // blockDim.x == 1024
    const int lane = tid & 63, wv = tid >> 6;
    const int i = blockIdx.x * 1024 + tid;
    int v = (i < n) ? counts[i] : 0;
    int x = v;
#pragma unroll
    for (int off = 1; off < 64; off <<= 1) {
        int t = __shfl_up(x, off);
        if (lane >= off) x += t;
    }
    if (lane == 63) wsum[wv] = x;
    __syncthreads();
    if (tid < 16) {
        int y = wsum[tid];
#pragma unroll
        for (int off = 1; off < 16; off <<= 1) {
            int t = __shfl_up(y, off);
            if (tid >= off) y += t;
        }
        wsum[tid] = y;
    }
    __syncthreads();
    int woff = (wv > 0) ? wsum[wv - 1] : 0;
    if (i < n) rowptr[i] = woff + x - v;   // block-local exclusive
    if (tid == 0) bsum[blockIdx.x] = wsum[15];
}

// merged tops-scan + add: each block re-scans bsum (nb <= 64) in one wave
__global__ void scan_add_tops(int* __restrict__ rowptr, const int* __restrict__ bsum,
                              int nb, int n) {
    __shared__ int off_s, tot_s;
    const int b = blockIdx.x;
    const int tid = threadIdx.x;           // blockDim.x == 1024
    if (tid < 64) {
        int v = (tid < nb) ? bsum[tid] : 0;
        int x = v;
#pragma unroll
        for (int off = 1; off < 64; off <<= 1) {
            int t = __shfl_up(x, off);
            if (tid >= off) x += t;
        }
        if (tid == 63) tot_s = x;          // grand total (lanes >= nb add 0)
        if (tid == b) off_s = x - v;       // exclusive prefix for this block
    }
    __syncthreads();
    int i = b * 1024 + tid;
    if (i < n) rowptr[i] += off_s;
    if (b == 0 && tid == 0) rowptr[n] = tot_s;
}

__global__ void scatter_kernel(const int* __restrict__ src, const int* __restrict__ dst,
                               const int* __restrict__ rowptr, int* __restrict__ cursor,
                               int* __restrict__ srcs, int E) {
    int i = blockIdx.x * blockDim.x + threadIdx.x;
    if (i < E) {
        int d = dst[i];
        int p = rowptr[d] + atomicAdd(&cursor[d], 1);
        srcs[p] = src[i];
    }
}

// ---------------- W pre-pack (both layers, one launch) ----------------
// B-frag (16x16x32): lane l, elem e -> B[k = ks*32 + (l>>4)*8 + e][col = ct*16 + (l&15)]
__global__ void pack_w_both(const float* __restrict__ W2, _Float16* __restrict__ Wp2,
                            const float* __restrict__ W3, _Float16* __restrict__ Wp3) {
    int idx = blockIdx.x * blockDim.x + threadIdx.x;
    const float* W; _Float16* Wp; int FOUT;
    if (idx < 2048) { W = W2; Wp = Wp2; FOUT = 128; }            // 8 ct * 4 ks * 64
    else {
        idx -= 2048;
        if (idx >= 4096) return;                                  // 16 ct * 4 ks * 64
        W = W3; Wp = Wp3; FOUT = 256;
    }
    int l = idx & 63;
    int ks = (idx >> 6) & 3;                                      // KS = 4
    int ct = idx >> 8;
    int kbase = ks * 32 + (l >> 4) * 8;
    int col = ct * 16 + (l & 15);
    h8v v;
#pragma unroll
    for (int e = 0; e < 8; e++) v[e] = (_Float16)W[(size_t)(kbase + e) * FOUT + col];
    *reinterpret_cast<h8v*>(&Wp[(size_t)idx * 8]) = v;
}

// ---------------- layer-1 fused GEMM + el/er (tiny FIN=6, vector ALU) -------
template <int FIN, int FOUT, int D>
__global__ void gemm_att(const float* __restrict__ A, const float* __restrict__ W,
                         const float* __restrict__ al, const float* __restrict__ ar,
                         _Float16* __restrict__ feat, float* __restrict__ el,
                         float* __restrict__ er, int N) {
    constexpr int R = 16;
    constexpr int H = FOUT / D;
    constexpr int T = FOUT / 2;
    __shared__ __align__(16) float As[FIN][R + 4];
    const int j = threadIdx.x;            // 0..T-1
    const int h0 = j / D;
    const int h1 = (j + T) / D;
    const float alv0 = al[j],     arv0 = ar[j];
    const float alv1 = al[j + T], arv1 = ar[j + T];
    const int row0 = blockIdx.x * R;

    for (int idx = threadIdx.x; idx < R * FIN; idx += T) {
        int r = idx / FIN, k = idx % FIN;
        int rr = row0 + r;
        As[k][r] = (rr < N) ? A[(size_t)rr * FIN + k] : 0.f;
    }
    __syncthreads();

    float acc0[R], acc1[R];
#pragma unroll
    for (int r = 0; r < R; r++) { acc0[r] = 0.f; acc1[r] = 0.f; }

    for (int k = 0; k < FIN; k++) {
        float w0 = W[(size_t)k * FOUT + j];
        float w1 = W[(size_t)k * FOUT + j + T];
        const float4* ap = reinterpret_cast<const float4*>(&As[k][0]);
        float av[16];
        *reinterpret_cast<float4*>(&av[0])  = ap[0];
        *reinterpret_cast<float4*>(&av[4])  = ap[1];
        *reinterpret_cast<float4*>(&av[8])  = ap[2];
        *reinterpret_cast<float4*>(&av[12]) = ap[3];
#pragma unroll
        for (int r = 0; r < R; r++) {
            acc0[r] += av[r] * w0;
            acc1[r] += av[r] * w1;
        }
    }

#pragma unroll
    for (int r = 0; r < R; r++) {
        int rr = row0 + r;
        if (rr >= N) break;
        float v0 = acc0[r], v1 = acc1[r];
        feat[(size_t)rr * FOUT + j] = (_Float16)v0;
        feat[(size_t)rr * FOUT + j + T] = (_Float16)v1;
        float vl0 = v0 * alv0, vr0 = v0 * arv0;
        float vl1 = v1 * alv1, vr1 = v1 * arv1;
#pragma unroll
        for (int off = D / 2; off >= 1; off >>= 1) {
            vl0 += __shfl_xor(vl0, off);
            vr0 += __shfl_xor(vr0, off);
            vl1 += __shfl_xor(vl1, off);
            vr1 += __shfl_xor(vr1, off);
        }
        if ((j % D) == 0) {
            el[(size_t)rr * H + h0] = vl0;
            er[(size_t)rr * H + h0] = vr0;
            el[(size_t)rr * H + h1] = vl1;
            er[(size_t)rr * H + h1] = vr1;
        }
    }
}

// ---------------- layers 2/3: MFMA fp16 GEMM + fused el/er ----------------
// A is pre-activated fp16 (bias+relu applied in the producing agg epilogue).
template <int K, int FOUT, int D>
__global__ __launch_bounds__(256)
void gemm_mfma(const _Float16* __restrict__ A, const _Float16* __restrict__ Wp,
               const float* __restrict__ al, const float* __restrict__ ar,
               _Float16* __restrict__ feat, float* __restrict__ el,
               float* __restrict__ er, int N) {
    constexpr int RB  = 32;
    constexpr int KS  = K / 32;           // 4 k-steps
    constexpr int CHW = FOUT / 2;         // cols per wave
    constexpr int CTW = CHW / 16;         // col-tiles per wave
    constexpr int CTH = D / 16;           // col-tiles per head
    constexpr int HW  = CTW / CTH;        // heads per wave (2)
    constexpr int H   = FOUT / D;
    constexpr int STR = K + 8;            // LDS row stride (fp16)
    __shared__ _Float16 As[RB * STR];
    const int tid = threadIdx.x;
    const int w  = tid >> 6;
    const int l  = tid & 63;
    const int rt = w >> 1;
    const int ch = w & 1;
    const int row0 = blockIdx.x * RB;

    // stage A tile: pure h8 copies (already fp16 + activated)
    constexpr int NV8 = RB * K / 8;
    for (int v = tid; v < NV8; v += 256) {
        int r  = v / (K / 8);
        int kv = (v % (K / 8)) * 8;
        int rr = row0 + r;
        h8v x = {};
        if (rr < N) x = *reinterpret_cast<const h8v*>(&A[(size_t)rr * K + kv]);
        *reinterpret_cast<h8v*>(&As[r * STR + kv]) = x;
    }
    __syncthreads();

    h8v afrag[KS];
    {
        const _Float16* base = &As[(rt * 16 + (l & 15)) * STR + ((l >> 4) * 8)];
#pragma unroll
        for (int ks = 0; ks < KS; ks++)
            afrag[ks] = *reinterpret_cast<const h8v*>(&base[ks * 32]);
    }

    const h8v* Wv = reinterpret_cast<const h8v*>(Wp);
    const int ct0 = ch * CTW;
    f4v acc[CTW];
#pragma unroll
    for (int c = 0; c < CTW; c++) acc[c] = (f4v){0.f, 0.f, 0.f, 0.f};

    h8v bfr[2][KS];
#pragma unroll
    for (int ks = 0; ks < KS; ks++) bfr[0][ks] = Wv[(size_t)((ct0 * KS + ks) * 64 + l)];
#pragma unroll
    for (int c = 0; c < CTW; c++) {
        const int cur = c & 1, nxt = cur ^ 1;
        if (c + 1 < CTW) {
#pragma unroll
            for (int ks = 0; ks < KS; ks++)
                bfr[nxt][ks] = Wv[(size_t)(((ct0 + c + 1) * KS + ks) * 64 + l)];
        }
#pragma unroll
        for (int ks = 0; ks < KS; ks++)
            acc[c] = __builtin_amdgcn_mfma_f32_16x16x32_f16(afrag[ks], bfr[cur][ks], acc[c], 0, 0, 0);
    }

    float elp[HW][4], erp[HW][4];
#pragma unroll
    for (int hh = 0; hh < HW; hh++)
#pragma unroll
        for (int r = 0; r < 4; r++) { elp[hh][r] = 0.f; erp[hh][r] = 0.f; }

#pragma unroll
    for (int c = 0; c < CTW; c++) {
        const int col = ch * CHW + c * 16 + (l & 15);
        const float alv = al[col], arv = ar[col];
        const int hh = c / CTH;
#pragma unroll
        for (int r = 0; r < 4; r++) {
            float v = acc[c][r];
            elp[hh][r] += v * alv;
            erp[hh][r] += v * arv;
            int rr = row0 + rt * 16 + (l >> 4) * 4 + r;
            if (rr < N) feat[(size_t)rr * FOUT + col] = (_Float16)v;
        }
    }
#pragma unroll
    for (int hh = 0; hh < HW; hh++) {
#pragma unroll
        for (int r = 0; r < 4; r++) {
            float v = elp[hh][r], u = erp[hh][r];
#pragma unroll
            for (int off = 8; off >= 1; off >>= 1) {
                v += __shfl_xor(v, off);
                u += __shfl_xor(u, off);
            }
            if ((l & 15) == 0) {
                int rr = row0 + rt * 16 + (l >> 4) * 4 + r;
                if (rr < N) {
                    int hg = ch * HW + hh;
                    el[(size_t)rr * H + hg] = v;
                    er[(size_t)rr * H + hg] = u;
                }
            }
        }
    }
}

// ---------------- fused single-pass edge softmax + aggregation ----------------
// No max-subtraction (mathematically identical; logits O(+-10), fp32 exp safe).
// Lane owns 8 contiguous channels; int4 srcs loads (align-peeled).
// FP16OUT: fuse relu(agg + bias) -> fp16 for the next MFMA GEMM (bit-identical
// to applying it at GEMM staging, which is where it happened before).
template <int HD, int D, bool FP16OUT>
__global__ __launch_bounds__(256)
void agg_fused(const h8v* __restrict__ featH8, const float* __restrict__ el,
               const float* __restrict__ er, const int* __restrict__ srcs,
               const int* __restrict__ rowptr, const float* __restrict__ bias,
               void* __restrict__ outp, int N) {
    constexpr int TPN = HD / 8;          // 16 (HD=128) or 32 (HD=256)
    constexpr int NPB = 256 / TPN;       // 16 or 8
    const int tid = threadIdx.x;
    const int ln = tid % TPN;
    const int node = blockIdx.x * NPB + tid / TPN;
    if (node >= N) return;
    const int h = ln / (D / 8);          // head of this lane's 8 channels
    const int beg = rowptr[node], end = rowptr[node + 1];
    const float ern = er[(size_t)node * 4 + h];

    float s = 0.f;
    f32x8 a0 = {0,0,0,0,0,0,0,0}, a1 = a0;

    int i = beg;
    int alend = (beg + 3) & ~3;
    if (alend > end) alend = end;
    for (; i < alend; i++) {             // peel to 16B alignment of srcs
        int u = srcs[i];
        float x = el[(size_t)u * 4 + h] + ern; x = x > 0.f ? x : 0.2f * x;
        h8v f = featH8[(size_t)u * TPN + ln];
        float w = __expf(x);
        s += w;
#pragma unroll
        for (int k = 0; k < 8; k++) a0[k] += w * (float)f[k];
    }
    for (; i + 4 <= end; i += 4) {
        int4 uu = *reinterpret_cast<const int4*>(&srcs[i]);
        float x0 = el[(size_t)uu.x * 4 + h] + ern; x0 = x0 > 0.f ? x0 : 0.2f * x0;
        float x1 = el[(size_t)uu.y * 4 + h] + ern; x1 = x1 > 0.f ? x1 : 0.2f * x1;
        float x2 = el[(size_t)uu.z * 4 + h] + ern; x2 = x2 > 0.f ? x2 : 0.2f * x2;
        float x3 = el[(size_t)uu.w * 4 + h] + ern; x3 = x3 > 0.f ? x3 : 0.2f * x3;
        h8v f0 = featH8[(size_t)uu.x * TPN + ln];
        h8v f1 = featH8[(size_t)uu.y * TPN + ln];
        h8v f2 = featH8[(size_t)uu.z * TPN + ln];
        h8v f3 = featH8[(size_t)uu.w * TPN + ln];
        float w0 = __expf(x0), w1 = __expf(x1);
        float w2 = __expf(x2), w3 = __expf(x3);
        s += (w0 + w1) + (w2 + w3);
#pragma unroll
        for (int k = 0; k < 8; k++) {
            a0[k] += w0 * (float)f0[k];
            a1[k] += w1 * (float)f1[k];
            a0[k] += w2 * (float)f2[k];
            a1[k] += w3 * (float)f3[k];
        }
    }
    for (; i < end; i++) {
        int u = srcs[i];
        float x = el[(size_t)u * 4 + h] + ern; x = x > 0.f ? x : 0.2f * x;
        h8v f = featH8[(size_t)u * TPN + ln];
        float w = __expf(x);
        s += w;
#pragma unroll
        for (int k = 0; k < 8; k++) a0[k] += w * (float)f[k];
    }
    const float inv = (s > 0.f) ? 1.f / s : 0.f;
    if constexpr (FP16OUT) {
        const float4 b0 = *reinterpret_cast<const float4*>(&bias[ln * 8]);
        const float4 b1v = *reinterpret_cast<const float4*>(&bias[ln * 8 + 4]);
        float bb[8] = {b0.x, b0.y, b0.z, b0.w, b1v.x, b1v.y, b1v.z, b1v.w};
        h8v o;
#pragma unroll
        for (int k = 0; k < 8; k++)
            o[k] = (_Float16)fmaxf((a0[k] + a1[k]) * inv + bb[k], 0.f);
        reinterpret_cast<h8v*>(outp)[(size_t)node * TPN + ln] = o;
    } else {
        f32x8 o;
#pragma unroll
        for (int k = 0; k < 8; k++) o[k] = (a0[k] + a1[k]) * inv;
        reinterpret_cast<f32x8*>(outp)[(size_t)node * TPN + ln] = o;
    }
}

// ---------------- batched-graph mean readout ----------------

__device__ __forceinline__ int lower_bound_i(const int* __restrict__ a, int n, int key) {
    int lo = 0, hi = n;
    while (lo < hi) {
        int mid = (lo + hi) >> 1;
        if (a[mid] < key) lo = mid + 1; else hi = mid;
    }
    return lo;
}

__global__ void readout_partial(const float* __restrict__ agg, const int* __restrict__ gid,
                                float* __restrict__ part, int N, int C, int SL) {
    int g = blockIdx.x / SL, slice = blockIdx.x % SL;
    int c = threadIdx.x;
    int start = lower_bound_i(gid, N, g);
    int end = lower_bound_i(gid, N, g + 1);
    float sum = 0.f;
    for (int n = start + slice; n < end; n += SL) sum += agg[(size_t)n * C + c];
    part[((size_t)g * SL + slice) * C + c] = sum;
}

__global__ void readout_final(const float* __restrict__ part, const float* __restrict__ b3,
                              const int* __restrict__ gid, float* __restrict__ out,
                              int N, int C, int SL) {
    int g = blockIdx.x, c = threadIdx.x;
    int start = lower_bound_i(gid, N, g);
    int end = lower_bound_i(gid, N, g + 1);
    int cnt = end - start;
    float s = 0.f;
    for (int k = 0; k < SL; k++) s += part[((size_t)g * SL + k) * C + c];
    out[(size_t)g * C + c] = (cnt > 0) ? s / (float)cnt + b3[c] : 0.f;
}

// ---------------- launch ----------------

extern "C" void kernel_launch(void* const* d_in, const int* in_sizes, int n_in,
                              void* d_out, int out_size, void* d_ws, size_t ws_size,
                              hipStream_t stream) {
    const float* feat0 = (const float*)d_in[0];
    const int* src = (const int*)d_in[1];
    const int* dst = (const int*)d_in[2];
    const int* gid = (const int*)d_in[3];
    const float* W1 = (const float*)d_in[4];
    const float* al1 = (const float*)d_in[5];
    const float* ar1 = (const float*)d_in[6];
    const float* b1 = (const float*)d_in[7];
    const float* W2 = (const float*)d_in[8];
    const float* al2 = (const float*)d_in[9];
    const float* ar2 = (const float*)d_in[10];
    const float* b2 = (const float*)d_in[11];
    const float* W3 = (const float*)d_in[12];
    const float* al3 = (const float*)d_in[13];
    const float* ar3 = (const float*)d_in[14];
    const float* b3 = (const float*)d_in[15];

    const int N = in_sizes[0] / 6;       // 30000
    const int E = in_sizes[1];           // 480000
    const int G = 64;
    const int SL = 8;
    float* out = (float*)d_out;

    char* wsp = (char*)d_ws;
    auto alloc = [&](size_t bytes) -> char* {
        char* p = wsp;
        wsp += (bytes + 255) & ~(size_t)255;
        return p;
    };
    int* counts   = (int*)alloc((size_t)N * 4);
    int* rowptr   = (int*)alloc((size_t)(N + 1) * 4);
    int* cursor   = (int*)alloc((size_t)N * 4);
    int* bsum     = (int*)alloc(64 * 4);
    int* srcs     = (int*)alloc((size_t)E * 4);
    float* el     = (float*)alloc((size_t)N * 4 * 4);
    float* er     = (float*)alloc((size_t)N * 4 * 4);
    _Float16* featH = (_Float16*)alloc((size_t)N * 256 * 2);  // GEMM out (gathered)
    _Float16* aggH  = (_Float16*)alloc((size_t)N * 128 * 2);  // activated agg out
    float* aggB   = (float*)alloc((size_t)N * 256 * 4);       // layer-3 agg (fp32)
    float* part   = (float*)alloc((size_t)G * SL * 256 * 4);
    _Float16* Wp2 = (_Float16*)alloc((size_t)128 * 128 * 2);
    _Float16* Wp3 = (_Float16*)alloc((size_t)128 * 256 * 2);

    // CSR build
    const int nb = (N + 1023) / 1024;
    const int zspan = (int)(((char*)bsum - (char*)counts) / 4) + 64;
    zero_i32<<<dim3((zspan + 255) / 256), dim3(256), 0, stream>>>(counts, zspan);
    hist_kernel<<<dim3((E + 255) / 256), dim3(256), 0, stream>>>(dst, counts, E);
    scan_block<<<dim3(nb), dim3(1024), 0, stream>>>(counts, rowptr, bsum, N);
    scan_add_tops<<<dim3(nb), dim3(1024), 0, stream>>>(rowptr, bsum, nb, N);
    scatter_kernel<<<dim3((E + 255) / 256), dim3(256), 0, stream>>>(
        src, dst, rowptr, cursor, srcs, E);

    // W pre-pack (both layers, fp16, MFMA B-frag order)
    pack_w_both<<<dim3(24), dim3(256), 0, stream>>>(W2, Wp2, W3, Wp3);

    // layer 1 (vector GEMM, K=6)
    gemm_att<6, 128, 32><<<dim3((N + 15) / 16), dim3(64), 0, stream>>>(
        feat0, W1, al1, ar1, featH, el, er, N);
    agg_fused<128, 32, true><<<dim3((N + 15) / 16), dim3(256), 0, stream>>>(
        (const h8v*)featH, el, er, srcs, rowptr, b1, aggH, N);

    // layer 2 (MFMA, pre-activated fp16 input)
    gemm_mfma<128, 128, 32><<<dim3((N + 31) / 32), dim3(256), 0, stream>>>(
        aggH, Wp2, al2, ar2, featH, el, er, N);
    agg_fused<128, 32, true><<<dim3((N + 15) / 16), dim3(256), 0, stream>>>(
        (const h8v*)featH, el, er, srcs, rowptr, b2, aggH, N);

    // layer 3 (MFMA)
    gemm_mfma<128, 256, 64><<<dim3((N + 31) / 32), dim3(256), 0, stream>>>(
        aggH, Wp3, al3, ar3, featH, el, er, N);
    agg_fused<256, 64, false><<<dim3((N + 7) / 8), dim3(256), 0, stream>>>(
        (const h8v*)featH, el, er, srcs, rowptr, nullptr, aggB, N);

    // readout
    readout_partial<<<dim3(G * SL), dim3(256), 0, stream>>>(aggB, gid, part, N, 256, SL);
    readout_final<<<dim3(G), dim3(256), 0, stream>>>(part, b3, gid, out, N, 256, SL);
}